// Round 14
// baseline (133.412 us; speedup 1.0000x reference)
//
#include <hip/hip_runtime.h>
#include <hip/hip_fp16.h>
#include <cstdint>
#include <cstddef>

#define BB 16
#define LL 2048
#define CC 512   // H*E
#define TK 7     // int(log(2048)) = 7
#define PDC(a) ((a) + ((a) >> 4))   // cf-unit LDS pad: +1 cf per 16
#define PSTR 1056                   // Ppart per-group stride (1025 used)
#define NG 128                      // fwd groups per batch (4 channels each)

typedef float2 cf;
typedef __attribute__((ext_vector_type(4))) float f32x4v;

__device__ inline cf cadd(cf a, cf b){ return make_float2(a.x + b.x, a.y + b.y); }
__device__ inline cf csub(cf a, cf b){ return make_float2(a.x - b.x, a.y - b.y); }
__device__ inline cf cmul(cf a, cf b){ return make_float2(a.x*b.x - a.y*b.y, a.x*b.y + a.y*b.x); }

// S*i*z : forward S=-1 -> (z.y, -z.x); inverse S=+1 -> (-z.y, z.x)
template<int S> __device__ inline cf crot(cf z){
  return (S < 0) ? make_float2(z.y, -z.x) : make_float2(-z.y, z.x);
}

template<int S> __device__ inline void dft4(cf* x){
  const cf t0 = cadd(x[0], x[2]), t1 = csub(x[0], x[2]);
  const cf t2 = cadd(x[1], x[3]), t3 = csub(x[1], x[3]);
  const cf r = crot<S>(t3);
  x[0] = cadd(t0, t2); x[2] = csub(t0, t2);
  x[1] = cadd(t1, r);  x[3] = csub(t1, r);
}

template<int S> __device__ inline void dft8(cf* x){
  cf e[4] = { x[0], x[2], x[4], x[6] };
  cf o[4] = { x[1], x[3], x[5], x[7] };
  dft4<S>(e); dft4<S>(o);
  const float H = 0.70710678118654752440f;
  o[1] = cmul(o[1], make_float2(H, (float)S * H));
  o[2] = crot<S>(o[2]);
  o[3] = cmul(o[3], make_float2(-H, (float)S * H));
  x[0] = cadd(e[0], o[0]); x[4] = csub(e[0], o[0]);
  x[1] = cadd(e[1], o[1]); x[5] = csub(e[1], o[1]);
  x[2] = cadd(e[2], o[2]); x[6] = csub(e[2], o[2]);
  x[3] = cadd(e[3], o[3]); x[7] = csub(e[3], o[3]);
}

struct Tw { cf w2[7], w3[7], w4a[3], w4b[3]; };

template<int S>
__device__ inline void make_tw(int tid, Tw& T){
  const float base = (float)S * 6.283185307179586f / 2048.0f;
  const int j7 = tid & 7, j63 = tid & 63;
#pragma unroll
  for (int i = 0; i < 7; ++i){
    float s, c;
    __sincosf(base * (float)(32 * (i + 1) * j7), &s, &c);  T.w2[i] = make_float2(c, s);
    __sincosf(base * (float)( 4 * (i + 1) * j63), &s, &c); T.w3[i] = make_float2(c, s);
  }
#pragma unroll
  for (int i = 0; i < 3; ++i){
    float s, c;
    __sincosf(base * (float)((i + 1) * tid), &s, &c);         T.w4a[i] = make_float2(c, s);
    __sincosf(base * (float)((i + 1) * (tid + 256)), &s, &c); T.w4b[i] = make_float2(c, s);
  }
}

// Stages 1-3 with DUAL buffers (used by fft_inv_topk only).
template<int S>
__device__ inline void fft_s123(cf* Bc, cf* Cc, cf* x, const Tw& T, int tid){
  dft8<S>(x);
#pragma unroll
  for (int t = 0; t < 8; ++t) Bc[PDC((tid << 3) + t)] = x[t];
  __syncthreads();
  {
    cf y[8];
#pragma unroll
    for (int t = 0; t < 8; ++t) y[t] = Bc[PDC(tid + (t << 8))];
#pragma unroll
    for (int t = 1; t < 8; ++t) y[t] = cmul(y[t], T.w2[t - 1]);
    dft8<S>(y);
    const int base = ((tid >> 3) << 6) + (tid & 7);
#pragma unroll
    for (int t = 0; t < 8; ++t) Cc[PDC(base + (t << 3))] = y[t];
  }
  __syncthreads();
  {
    cf y[8];
#pragma unroll
    for (int t = 0; t < 8; ++t) y[t] = Cc[PDC(tid + (t << 8))];
#pragma unroll
    for (int t = 1; t < 8; ++t) y[t] = cmul(y[t], T.w3[t - 1]);
    dft8<S>(y);
    const int base = ((tid >> 6) << 9) + (tid & 63);
#pragma unroll
    for (int t = 0; t < 8; ++t) Bc[PDC(base + (t << 6))] = y[t];
  }
  __syncthreads();
}

// ---------------------------------------------------------------------------
// Phase 1: z[b][c][t] = half2(q[b][t][c], k[b][t][c])  (64x64 fp16 LDS tile)
// ---------------------------------------------------------------------------
__global__ __launch_bounds__(256) void transpose_pack(const float* __restrict__ q,
                                                      const float* __restrict__ k,
                                                      __half2* __restrict__ z){
  int bid = blockIdx.x;
  const int tt = bid & 31; bid >>= 5;
  const int ct = bid & 7;  bid >>= 3;
  const int b = bid;
  const int t0 = tt << 6, c0 = ct << 6;
  __shared__ __half2 T[64][69];   // [t][c], pad 69 to break bank strides
  const int tid = threadIdx.x;
  const size_t inbase = ((size_t)b * LL + t0) * CC + c0;
  const int c4 = (tid & 15) << 2;
  f32x4v a[4], e[4];
#pragma unroll
  for (int p2 = 0; p2 < 4; ++p2){
    const int row = (p2 << 4) + (tid >> 4);
    a[p2] = __builtin_nontemporal_load(
        reinterpret_cast<const f32x4v*>(q + inbase + (size_t)row * CC + c4));
    e[p2] = __builtin_nontemporal_load(
        reinterpret_cast<const f32x4v*>(k + inbase + (size_t)row * CC + c4));
  }
#pragma unroll
  for (int p2 = 0; p2 < 4; ++p2){
    const int row = (p2 << 4) + (tid >> 4);
    T[row][c4 + 0] = __floats2half2_rn(a[p2][0], e[p2][0]);
    T[row][c4 + 1] = __floats2half2_rn(a[p2][1], e[p2][1]);
    T[row][c4 + 2] = __floats2half2_rn(a[p2][2], e[p2][2]);
    T[row][c4 + 3] = __floats2half2_rn(a[p2][3], e[p2][3]);
  }
  __syncthreads();
  const size_t outbase = ((size_t)b * CC + c0) * LL + (size_t)t0;
#pragma unroll
  for (int it = 0; it < 4; ++it){
    const int idx = (it << 8) + tid;
    const int c = idx >> 4;                 // c_local 0..63
    const int t4 = (idx & 15) << 2;         // t_local base (x4)
    const __half2 u0 = T[t4 + 0][c], u1 = T[t4 + 1][c];
    const __half2 u2 = T[t4 + 2][c], u3 = T[t4 + 3][c];
    uint4 w;
    w.x = *reinterpret_cast<const uint*>(&u0);
    w.y = *reinterpret_cast<const uint*>(&u1);
    w.z = *reinterpret_cast<const uint*>(&u2);
    w.w = *reinterpret_cast<const uint*>(&u3);
    *reinterpret_cast<uint4*>(&z[outbase + (size_t)c * LL + t4]) = w;
  }
}

// ---------------------------------------------------------------------------
// Phase 2: per (b, group of 4 channels): forward FFT, single 17.4 KB LDS
// buffer, 8 blocks/CU. P[f] for f in [0,1024] (Hermitian rest in reduce_P).
// ---------------------------------------------------------------------------
__global__ __launch_bounds__(256) void fft_fwd(const __half2* __restrict__ z,
                                               float2* __restrict__ Ppart){
  int bid = blockIdx.x;
  const int g = bid & (NG - 1); const int b = bid >> 7;
  const int tid = threadIdx.x;
  __shared__ cf B[2176];
  Tw T; make_tw<-1>(tid, T);
  const __half2* zg = z + (((size_t)b * CC + (size_t)g * 4) << 11);
  float accRe[4] = {0,0,0,0};
  float accIm[4] = {0,0,0,0};
  float acc1024 = 0.f;
  __half2 h[8];
#pragma unroll
  for (int t = 0; t < 8; ++t) h[t] = zg[tid + (t << 8)];
  for (int ch = 0; ch < 4; ++ch){
    cf x[8];
#pragma unroll
    for (int t = 0; t < 8; ++t) x[t] = __half22float2(h[t]);
    if (ch < 3){
      const __half2* zn = zg + ((size_t)(ch + 1) << 11);
#pragma unroll
      for (int t = 0; t < 8; ++t) h[t] = zn[tid + (t << 8)];
    }
    // stage 1 (regs)
    dft8<-1>(x);
    __syncthreads();                       // prior combine reads of B done
#pragma unroll
    for (int t = 0; t < 8; ++t) B[PDC((tid << 3) + t)] = x[t];
    __syncthreads();
    // stage 2
    cf y[8];
#pragma unroll
    for (int t = 0; t < 8; ++t) y[t] = B[PDC(tid + (t << 8))];
#pragma unroll
    for (int t = 1; t < 8; ++t) y[t] = cmul(y[t], T.w2[t - 1]);
    dft8<-1>(y);
    __syncthreads();
    {
      const int base = ((tid >> 3) << 6) + (tid & 7);
#pragma unroll
      for (int t = 0; t < 8; ++t) B[PDC(base + (t << 3))] = y[t];
    }
    __syncthreads();
    // stage 3
#pragma unroll
    for (int t = 0; t < 8; ++t) y[t] = B[PDC(tid + (t << 8))];
#pragma unroll
    for (int t = 1; t < 8; ++t) y[t] = cmul(y[t], T.w3[t - 1]);
    dft8<-1>(y);
    __syncthreads();
    {
      const int base = ((tid >> 6) << 9) + (tid & 63);
#pragma unroll
      for (int t = 0; t < 8; ++t) B[PDC(base + (t << 6))] = y[t];
    }
    __syncthreads();
    // stage 4 (in-place: reads/writes only this thread's slots j+512t)
    cf y0[4], y1[4];
#pragma unroll
    for (int t = 0; t < 4; ++t) y0[t] = B[PDC(tid + (t << 9))];
#pragma unroll
    for (int t = 0; t < 4; ++t) y1[t] = B[PDC(tid + 256 + (t << 9))];
#pragma unroll
    for (int t = 1; t < 4; ++t){
      y0[t] = cmul(y0[t], T.w4a[t - 1]);
      y1[t] = cmul(y1[t], T.w4b[t - 1]);
    }
    dft4<-1>(y0); dft4<-1>(y1);
#pragma unroll
    for (int t = 0; t < 4; ++t) B[PDC(tid + (t << 9))] = y0[t];
#pragma unroll
    for (int t = 0; t < 4; ++t) B[PDC(tid + 256 + (t << 9))] = y1[t];
    __syncthreads();
    // combine for f = tid + 256r, r<4: A = own regs, Bv = B[2048-f]
    const cf Areg[4] = { y0[0], y1[0], y0[1], y1[1] };
#pragma unroll
    for (int r = 0; r < 4; ++r){
      const int f = tid + (r << 8);
      const int p = (2048 - f) & 2047;
      const cf A = Areg[r];
      const cf Bv = B[PDC(p)];
      accRe[r] += 0.5f  * (Bv.y * A.x + Bv.x * A.y);
      accIm[r] += 0.25f * (A.x * A.x + A.y * A.y - Bv.x * Bv.x - Bv.y * Bv.y);
    }
    if (tid == 0){
      const cf A = y0[2];   // f = 1024, self-mirror: Re = Ar*Ai, Im = 0
      acc1024 += A.x * A.y;
    }
  }
  float2* pp = Ppart + ((size_t)b * NG + g) * PSTR;
#pragma unroll
  for (int r = 0; r < 4; ++r)
    pp[tid + (r << 8)] = make_float2(accRe[r], accIm[r]);
  if (tid == 0) pp[1024] = make_float2(acc1024, 0.f);
}

// ---------------------------------------------------------------------------
// Phase 2b: P[b,f] = sum_g Ppart[b,g,min(f,2048-f)], conj for f>1024.
// ---------------------------------------------------------------------------
__global__ __launch_bounds__(256) void reduce_P(const float2* __restrict__ Ppart,
                                                float2* __restrict__ P){
  const int gid = blockIdx.x * 256 + threadIdx.x;  // 0..32767
  const int b = gid >> 11, f = gid & 2047;
  const int src = (f <= 1024) ? f : 2048 - f;
  const float sgn = (f <= 1024) ? 1.f : -1.f;
  float sr = 0.f, si = 0.f;
#pragma unroll 8
  for (int g = 0; g < NG; ++g){
    const float2 v = Ppart[((size_t)b * NG + g) * PSTR + src];
    sr += v.x; si += v.y;
  }
  P[((size_t)b << 11) + f] = make_float2(sr, sgn * si);
}

// ---------------------------------------------------------------------------
// Phase 3: per b: inverse FFT of P, scale -> mv; fused top-7 + softmax.
// ---------------------------------------------------------------------------
__global__ __launch_bounds__(256) void fft_inv_topk(const float2* __restrict__ P,
                                                    int* __restrict__ delays,
                                                    float* __restrict__ probs){
  const int b = blockIdx.x;
  const int tid = threadIdx.x;
  __shared__ cf Bc[2176];
  __shared__ cf Cc[2176];
  __shared__ float vals[2048];
  __shared__ float rv[256]; __shared__ int ri[256];
  __shared__ float wsel[TK]; __shared__ int dsel[TK];
  Tw T; make_tw<1>(tid, T);
  cf x[8];
#pragma unroll
  for (int t = 0; t < 8; ++t) x[t] = P[((size_t)b << 11) + tid + (t << 8)];
  fft_s123<1>(Bc, Cc, x, T, tid);
  const float scale = 1.0f / (2048.0f * 512.0f);
  { // stage 4 in regs; write vals[j + 512t] directly
#pragma unroll
    for (int hh = 0; hh < 2; ++hh){
      const int j = tid + (hh << 8);
      cf y[4];
#pragma unroll
      for (int t = 0; t < 4; ++t) y[t] = Bc[PDC(j + (t << 9))];
      const cf* w = hh ? T.w4b : T.w4a;
#pragma unroll
      for (int t = 1; t < 4; ++t) y[t] = cmul(y[t], w[t - 1]);
      dft4<1>(y);
#pragma unroll
      for (int t = 0; t < 4; ++t) vals[j + (t << 9)] = y[t].x * scale;
    }
  }
  __syncthreads();
  for (int kk = 0; kk < TK; ++kk){
    float best = -1e30f; int bi = LL;
    for (int i = tid; i < LL; i += 256){
      const float xv = vals[i];
      if (xv > best){ best = xv; bi = i; }
    }
    rv[tid] = best; ri[tid] = bi;
    __syncthreads();
    for (int s = 128; s > 0; s >>= 1){
      if (tid < s){
        const float ov = rv[tid + s]; const int oi = ri[tid + s];
        if (ov > rv[tid] || (ov == rv[tid] && oi < ri[tid])){ rv[tid] = ov; ri[tid] = oi; }
      }
      __syncthreads();
    }
    if (tid == 0){ wsel[kk] = rv[0]; dsel[kk] = ri[0]; vals[ri[0]] = -1e30f; }
    __syncthreads();
  }
  if (tid == 0){
    const float m = wsel[0];
    float e[TK], ssum = 0.f;
#pragma unroll
    for (int i = 0; i < TK; ++i){ e[i] = expf(wsel[i] - m); ssum += e[i]; }
    const float inv = 1.0f / ssum;
#pragma unroll
    for (int i = 0; i < TK; ++i){
      probs[b * TK + i] = e[i] * inv;
      delays[b * TK + i] = dsel[i];
    }
  }
}

// ---------------------------------------------------------------------------
// Phase 4 (software-pipelined persistent): out[b,t,:] = sum_k p_k * v-gather.
// 2048 blocks; block (xcd, j0) does 8 unrolled iterations it = j0 + s*256
// over its XCD's two batches (XCD-L2 affinity). Iteration s issues the 7
// gather loads of iteration s+1 into the other named register set (ping-pong
// by s&1, compile-time) so 7 loads stay in flight across compute+store.
// ---------------------------------------------------------------------------
__global__ __launch_bounds__(256) void agg_out(const float* __restrict__ v,
                                               const int* __restrict__ delays,
                                               const float* __restrict__ probs,
                                               float* __restrict__ out){
  const int bid = blockIdx.x;            // 2048
  const int xcd = bid & 7;
  const int j0  = bid >> 3;              // 0..255
  const int tid = threadIdx.x;
  const int row_off = tid >> 7;          // 0..1 (2 rows per iteration)
  const int slot = tid & 127;            // float4 slot within row
  const int b0 = xcd << 1;
  float p0[TK], p1[TK]; int d0[TK], d1[TK];
#pragma unroll
  for (int k = 0; k < TK; ++k){
    p0[k] = probs[b0 * TK + k];        d0[k] = delays[b0 * TK + k];
    p1[k] = probs[(b0 + 1) * TK + k];  d1[k] = delays[(b0 + 1) * TK + k];
  }
  const f32x4v* v4 = reinterpret_cast<const f32x4v*>(v);
  f32x4v A[TK], Bv[TK];

  // issue loads for iteration s into X
#define AGG_ISSUE(s, X)                                                       \
  {                                                                           \
    const int it_ = j0 + ((s) << 8);                                          \
    const int seg_ = it_ >> 10;                                               \
    const int b_ = b0 + seg_;                                                 \
    const int t_ = ((it_ << 1) + row_off) & (LL - 1);                         \
    _Pragma("unroll")                                                         \
    for (int k = 0; k < TK; ++k){                                             \
      const int dk_ = seg_ ? d1[k] : d0[k];                                   \
      const int src_ = (t_ + dk_) & (LL - 1);                                 \
      X[k] = v4[(((size_t)((b_ << 11) + src_)) << 7) + slot];                 \
    }                                                                         \
  }

  AGG_ISSUE(0, A);
#pragma unroll
  for (int s = 0; s < 8; ++s){
    if (s & 1){ if (s < 7) AGG_ISSUE(s + 1, A); }
    else      { if (s < 7) AGG_ISSUE(s + 1, Bv); }
    const int it = j0 + (s << 8);
    const int seg = it >> 10;
    const int b = b0 + seg;
    const int t = ((it << 1) + row_off) & (LL - 1);
    f32x4v acc = {0.f, 0.f, 0.f, 0.f};
    if (s & 1){
#pragma unroll
      for (int k = 0; k < TK; ++k) acc += Bv[k] * (seg ? p1[k] : p0[k]);
    } else {
#pragma unroll
      for (int k = 0; k < TK; ++k) acc += A[k] * (seg ? p1[k] : p0[k]);
    }
    f32x4v* o = reinterpret_cast<f32x4v*>(out) + (((size_t)((b << 11) + t)) << 7) + slot;
    __builtin_nontemporal_store(acc, o);
  }
#undef AGG_ISSUE
}

// ---------------------------------------------------------------------------
extern "C" void kernel_launch(void* const* d_in, const int* in_sizes, int n_in,
                              void* d_out, int out_size, void* d_ws, size_t ws_size,
                              hipStream_t stream){
  const float* q = (const float*)d_in[0];
  const float* k = (const float*)d_in[1];
  const float* v = (const float*)d_in[2];
  float* out = (float*)d_out;

  char* ws = (char*)d_ws;
  const size_t Z_BYTES  = (size_t)BB * CC * LL * sizeof(__half2);   // 67.1 MB
  const size_t PP_BYTES = (size_t)BB * NG * PSTR * sizeof(float2);  // 17.3 MB
  const size_t P_BYTES  = (size_t)BB * LL * sizeof(float2);         // 256 KB
  __half2* zbuf = (__half2*)ws;
  float2* Ppart = (float2*)(ws + Z_BYTES);
  float2* Pbuf  = (float2*)(ws + Z_BYTES + PP_BYTES);
  int* delays = (int*)(ws + Z_BYTES + PP_BYTES + P_BYTES);
  float* probs = (float*)(ws + Z_BYTES + PP_BYTES + P_BYTES + 1024);

  hipLaunchKernelGGL(transpose_pack, dim3(BB * 32 * 8), dim3(256), 0, stream, q, k, zbuf);
  hipLaunchKernelGGL(fft_fwd, dim3(BB * NG), dim3(256), 0, stream, zbuf, Ppart);
  hipLaunchKernelGGL(reduce_P, dim3((BB * LL) / 256), dim3(256), 0, stream, Ppart, Pbuf);
  hipLaunchKernelGGL(fft_inv_topk, dim3(BB), dim3(256), 0, stream, Pbuf, delays, probs);
  hipLaunchKernelGGL(agg_out, dim3(2048), dim3(256), 0, stream,
                     v, delays, probs, out);
}

// Round 15
// 123.195 us; speedup vs baseline: 1.0829x; 1.0829x over previous
//
#include <hip/hip_runtime.h>
#include <hip/hip_fp16.h>
#include <cstdint>
#include <cstddef>

#define BB 16
#define LL 2048
#define CC 512   // H*E
#define TK 7     // int(log(2048)) = 7
#define PDC(a) ((a) + ((a) >> 4))   // cf-unit LDS pad: +1 cf per 16
#define PSTR 1056                   // Ppart per-group stride (1025 used)
#define NG 128                      // fwd groups per batch (4 channels each)

typedef float2 cf;
typedef __attribute__((ext_vector_type(4))) float f32x4v;

__device__ inline cf cadd(cf a, cf b){ return make_float2(a.x + b.x, a.y + b.y); }
__device__ inline cf csub(cf a, cf b){ return make_float2(a.x - b.x, a.y - b.y); }
__device__ inline cf cmul(cf a, cf b){ return make_float2(a.x*b.x - a.y*b.y, a.x*b.y + a.y*b.x); }

// S*i*z : forward S=-1 -> (z.y, -z.x); inverse S=+1 -> (-z.y, z.x)
template<int S> __device__ inline cf crot(cf z){
  return (S < 0) ? make_float2(z.y, -z.x) : make_float2(-z.y, z.x);
}

template<int S> __device__ inline void dft4(cf* x){
  const cf t0 = cadd(x[0], x[2]), t1 = csub(x[0], x[2]);
  const cf t2 = cadd(x[1], x[3]), t3 = csub(x[1], x[3]);
  const cf r = crot<S>(t3);
  x[0] = cadd(t0, t2); x[2] = csub(t0, t2);
  x[1] = cadd(t1, r);  x[3] = csub(t1, r);
}

template<int S> __device__ inline void dft8(cf* x){
  cf e[4] = { x[0], x[2], x[4], x[6] };
  cf o[4] = { x[1], x[3], x[5], x[7] };
  dft4<S>(e); dft4<S>(o);
  const float H = 0.70710678118654752440f;
  o[1] = cmul(o[1], make_float2(H, (float)S * H));
  o[2] = crot<S>(o[2]);
  o[3] = cmul(o[3], make_float2(-H, (float)S * H));
  x[0] = cadd(e[0], o[0]); x[4] = csub(e[0], o[0]);
  x[1] = cadd(e[1], o[1]); x[5] = csub(e[1], o[1]);
  x[2] = cadd(e[2], o[2]); x[6] = csub(e[2], o[2]);
  x[3] = cadd(e[3], o[3]); x[7] = csub(e[3], o[3]);
}

struct Tw { cf w2[7], w3[7], w4a[3], w4b[3]; };

template<int S>
__device__ inline void make_tw(int tid, Tw& T){
  const float base = (float)S * 6.283185307179586f / 2048.0f;
  const int j7 = tid & 7, j63 = tid & 63;
#pragma unroll
  for (int i = 0; i < 7; ++i){
    float s, c;
    __sincosf(base * (float)(32 * (i + 1) * j7), &s, &c);  T.w2[i] = make_float2(c, s);
    __sincosf(base * (float)( 4 * (i + 1) * j63), &s, &c); T.w3[i] = make_float2(c, s);
  }
#pragma unroll
  for (int i = 0; i < 3; ++i){
    float s, c;
    __sincosf(base * (float)((i + 1) * tid), &s, &c);         T.w4a[i] = make_float2(c, s);
    __sincosf(base * (float)((i + 1) * (tid + 256)), &s, &c); T.w4b[i] = make_float2(c, s);
  }
}

// Stages 1-3 with DUAL buffers (used by fft_inv_topk only).
template<int S>
__device__ inline void fft_s123(cf* Bc, cf* Cc, cf* x, const Tw& T, int tid){
  dft8<S>(x);
#pragma unroll
  for (int t = 0; t < 8; ++t) Bc[PDC((tid << 3) + t)] = x[t];
  __syncthreads();
  {
    cf y[8];
#pragma unroll
    for (int t = 0; t < 8; ++t) y[t] = Bc[PDC(tid + (t << 8))];
#pragma unroll
    for (int t = 1; t < 8; ++t) y[t] = cmul(y[t], T.w2[t - 1]);
    dft8<S>(y);
    const int base = ((tid >> 3) << 6) + (tid & 7);
#pragma unroll
    for (int t = 0; t < 8; ++t) Cc[PDC(base + (t << 3))] = y[t];
  }
  __syncthreads();
  {
    cf y[8];
#pragma unroll
    for (int t = 0; t < 8; ++t) y[t] = Cc[PDC(tid + (t << 8))];
#pragma unroll
    for (int t = 1; t < 8; ++t) y[t] = cmul(y[t], T.w3[t - 1]);
    dft8<S>(y);
    const int base = ((tid >> 6) << 9) + (tid & 63);
#pragma unroll
    for (int t = 0; t < 8; ++t) Bc[PDC(base + (t << 6))] = y[t];
  }
  __syncthreads();
}

// ---------------------------------------------------------------------------
// Phase 1: z[b][c][t] = half2(q[b][t][c], k[b][t][c])  (64x64 fp16 LDS tile)
// ---------------------------------------------------------------------------
__global__ __launch_bounds__(256) void transpose_pack(const float* __restrict__ q,
                                                      const float* __restrict__ k,
                                                      __half2* __restrict__ z){
  int bid = blockIdx.x;
  const int tt = bid & 31; bid >>= 5;
  const int ct = bid & 7;  bid >>= 3;
  const int b = bid;
  const int t0 = tt << 6, c0 = ct << 6;
  __shared__ __half2 T[64][69];   // [t][c], pad 69 to break bank strides
  const int tid = threadIdx.x;
  const size_t inbase = ((size_t)b * LL + t0) * CC + c0;
  const int c4 = (tid & 15) << 2;
  f32x4v a[4], e[4];
#pragma unroll
  for (int p2 = 0; p2 < 4; ++p2){
    const int row = (p2 << 4) + (tid >> 4);
    a[p2] = __builtin_nontemporal_load(
        reinterpret_cast<const f32x4v*>(q + inbase + (size_t)row * CC + c4));
    e[p2] = __builtin_nontemporal_load(
        reinterpret_cast<const f32x4v*>(k + inbase + (size_t)row * CC + c4));
  }
#pragma unroll
  for (int p2 = 0; p2 < 4; ++p2){
    const int row = (p2 << 4) + (tid >> 4);
    T[row][c4 + 0] = __floats2half2_rn(a[p2][0], e[p2][0]);
    T[row][c4 + 1] = __floats2half2_rn(a[p2][1], e[p2][1]);
    T[row][c4 + 2] = __floats2half2_rn(a[p2][2], e[p2][2]);
    T[row][c4 + 3] = __floats2half2_rn(a[p2][3], e[p2][3]);
  }
  __syncthreads();
  const size_t outbase = ((size_t)b * CC + c0) * LL + (size_t)t0;
#pragma unroll
  for (int it = 0; it < 4; ++it){
    const int idx = (it << 8) + tid;
    const int c = idx >> 4;                 // c_local 0..63
    const int t4 = (idx & 15) << 2;         // t_local base (x4)
    const __half2 u0 = T[t4 + 0][c], u1 = T[t4 + 1][c];
    const __half2 u2 = T[t4 + 2][c], u3 = T[t4 + 3][c];
    uint4 w;
    w.x = *reinterpret_cast<const uint*>(&u0);
    w.y = *reinterpret_cast<const uint*>(&u1);
    w.z = *reinterpret_cast<const uint*>(&u2);
    w.w = *reinterpret_cast<const uint*>(&u3);
    *reinterpret_cast<uint4*>(&z[outbase + (size_t)c * LL + t4]) = w;
  }
}

// ---------------------------------------------------------------------------
// Phase 2: per (b, group of 4 channels): forward FFT, single 17.4 KB LDS
// buffer, 8 blocks/CU. P[f] for f in [0,1024] (Hermitian rest in reduce_P).
// ---------------------------------------------------------------------------
__global__ __launch_bounds__(256) void fft_fwd(const __half2* __restrict__ z,
                                               float2* __restrict__ Ppart){
  int bid = blockIdx.x;
  const int g = bid & (NG - 1); const int b = bid >> 7;
  const int tid = threadIdx.x;
  __shared__ cf B[2176];
  Tw T; make_tw<-1>(tid, T);
  const __half2* zg = z + (((size_t)b * CC + (size_t)g * 4) << 11);
  float accRe[4] = {0,0,0,0};
  float accIm[4] = {0,0,0,0};
  float acc1024 = 0.f;
  __half2 h[8];
#pragma unroll
  for (int t = 0; t < 8; ++t) h[t] = zg[tid + (t << 8)];
  for (int ch = 0; ch < 4; ++ch){
    cf x[8];
#pragma unroll
    for (int t = 0; t < 8; ++t) x[t] = __half22float2(h[t]);
    if (ch < 3){
      const __half2* zn = zg + ((size_t)(ch + 1) << 11);
#pragma unroll
      for (int t = 0; t < 8; ++t) h[t] = zn[tid + (t << 8)];
    }
    // stage 1 (regs)
    dft8<-1>(x);
    __syncthreads();                       // prior combine reads of B done
#pragma unroll
    for (int t = 0; t < 8; ++t) B[PDC((tid << 3) + t)] = x[t];
    __syncthreads();
    // stage 2
    cf y[8];
#pragma unroll
    for (int t = 0; t < 8; ++t) y[t] = B[PDC(tid + (t << 8))];
#pragma unroll
    for (int t = 1; t < 8; ++t) y[t] = cmul(y[t], T.w2[t - 1]);
    dft8<-1>(y);
    __syncthreads();
    {
      const int base = ((tid >> 3) << 6) + (tid & 7);
#pragma unroll
      for (int t = 0; t < 8; ++t) B[PDC(base + (t << 3))] = y[t];
    }
    __syncthreads();
    // stage 3
#pragma unroll
    for (int t = 0; t < 8; ++t) y[t] = B[PDC(tid + (t << 8))];
#pragma unroll
    for (int t = 1; t < 8; ++t) y[t] = cmul(y[t], T.w3[t - 1]);
    dft8<-1>(y);
    __syncthreads();
    {
      const int base = ((tid >> 6) << 9) + (tid & 63);
#pragma unroll
      for (int t = 0; t < 8; ++t) B[PDC(base + (t << 6))] = y[t];
    }
    __syncthreads();
    // stage 4 (in-place: reads/writes only this thread's slots j+512t)
    cf y0[4], y1[4];
#pragma unroll
    for (int t = 0; t < 4; ++t) y0[t] = B[PDC(tid + (t << 9))];
#pragma unroll
    for (int t = 0; t < 4; ++t) y1[t] = B[PDC(tid + 256 + (t << 9))];
#pragma unroll
    for (int t = 1; t < 4; ++t){
      y0[t] = cmul(y0[t], T.w4a[t - 1]);
      y1[t] = cmul(y1[t], T.w4b[t - 1]);
    }
    dft4<-1>(y0); dft4<-1>(y1);
#pragma unroll
    for (int t = 0; t < 4; ++t) B[PDC(tid + (t << 9))] = y0[t];
#pragma unroll
    for (int t = 0; t < 4; ++t) B[PDC(tid + 256 + (t << 9))] = y1[t];
    __syncthreads();
    // combine for f = tid + 256r, r<4: A = own regs, Bv = B[2048-f]
    const cf Areg[4] = { y0[0], y1[0], y0[1], y1[1] };
#pragma unroll
    for (int r = 0; r < 4; ++r){
      const int f = tid + (r << 8);
      const int p = (2048 - f) & 2047;
      const cf A = Areg[r];
      const cf Bv = B[PDC(p)];
      accRe[r] += 0.5f  * (Bv.y * A.x + Bv.x * A.y);
      accIm[r] += 0.25f * (A.x * A.x + A.y * A.y - Bv.x * Bv.x - Bv.y * Bv.y);
    }
    if (tid == 0){
      const cf A = y0[2];   // f = 1024, self-mirror: Re = Ar*Ai, Im = 0
      acc1024 += A.x * A.y;
    }
  }
  float2* pp = Ppart + ((size_t)b * NG + g) * PSTR;
#pragma unroll
  for (int r = 0; r < 4; ++r)
    pp[tid + (r << 8)] = make_float2(accRe[r], accIm[r]);
  if (tid == 0) pp[1024] = make_float2(acc1024, 0.f);
}

// ---------------------------------------------------------------------------
// Phase 2b: P[b,f] = sum_g Ppart[b,g,min(f,2048-f)], conj for f>1024.
// ---------------------------------------------------------------------------
__global__ __launch_bounds__(256) void reduce_P(const float2* __restrict__ Ppart,
                                                float2* __restrict__ P){
  const int gid = blockIdx.x * 256 + threadIdx.x;  // 0..32767
  const int b = gid >> 11, f = gid & 2047;
  const int src = (f <= 1024) ? f : 2048 - f;
  const float sgn = (f <= 1024) ? 1.f : -1.f;
  float sr = 0.f, si = 0.f;
#pragma unroll 8
  for (int g = 0; g < NG; ++g){
    const float2 v = Ppart[((size_t)b * NG + g) * PSTR + src];
    sr += v.x; si += v.y;
  }
  P[((size_t)b << 11) + f] = make_float2(sr, sgn * si);
}

// ---------------------------------------------------------------------------
// Phase 3: per b: inverse FFT of P, scale -> mv; fused top-7 + softmax.
// ---------------------------------------------------------------------------
__global__ __launch_bounds__(256) void fft_inv_topk(const float2* __restrict__ P,
                                                    int* __restrict__ delays,
                                                    float* __restrict__ probs){
  const int b = blockIdx.x;
  const int tid = threadIdx.x;
  __shared__ cf Bc[2176];
  __shared__ cf Cc[2176];
  __shared__ float vals[2048];
  __shared__ float rv[256]; __shared__ int ri[256];
  __shared__ float wsel[TK]; __shared__ int dsel[TK];
  Tw T; make_tw<1>(tid, T);
  cf x[8];
#pragma unroll
  for (int t = 0; t < 8; ++t) x[t] = P[((size_t)b << 11) + tid + (t << 8)];
  fft_s123<1>(Bc, Cc, x, T, tid);
  const float scale = 1.0f / (2048.0f * 512.0f);
  { // stage 4 in regs; write vals[j + 512t] directly
#pragma unroll
    for (int hh = 0; hh < 2; ++hh){
      const int j = tid + (hh << 8);
      cf y[4];
#pragma unroll
      for (int t = 0; t < 4; ++t) y[t] = Bc[PDC(j + (t << 9))];
      const cf* w = hh ? T.w4b : T.w4a;
#pragma unroll
      for (int t = 1; t < 4; ++t) y[t] = cmul(y[t], w[t - 1]);
      dft4<1>(y);
#pragma unroll
      for (int t = 0; t < 4; ++t) vals[j + (t << 9)] = y[t].x * scale;
    }
  }
  __syncthreads();
  for (int kk = 0; kk < TK; ++kk){
    float best = -1e30f; int bi = LL;
    for (int i = tid; i < LL; i += 256){
      const float xv = vals[i];
      if (xv > best){ best = xv; bi = i; }
    }
    rv[tid] = best; ri[tid] = bi;
    __syncthreads();
    for (int s = 128; s > 0; s >>= 1){
      if (tid < s){
        const float ov = rv[tid + s]; const int oi = ri[tid + s];
        if (ov > rv[tid] || (ov == rv[tid] && oi < ri[tid])){ rv[tid] = ov; ri[tid] = oi; }
      }
      __syncthreads();
    }
    if (tid == 0){ wsel[kk] = rv[0]; dsel[kk] = ri[0]; vals[ri[0]] = -1e30f; }
    __syncthreads();
  }
  if (tid == 0){
    const float m = wsel[0];
    float e[TK], ssum = 0.f;
#pragma unroll
    for (int i = 0; i < TK; ++i){ e[i] = expf(wsel[i] - m); ssum += e[i]; }
    const float inv = 1.0f / ssum;
#pragma unroll
    for (int i = 0; i < TK; ++i){
      probs[b * TK + i] = e[i] * inv;
      delays[b * TK + i] = dsel[i];
    }
  }
}

// ---------------------------------------------------------------------------
// Phase 4 (DMA-pipelined): out[b,t,:] = sum_k p_k * v[b,(t+d_k)%L,:].
// 2048 blocks; block = (xcd, 16-contiguous-row span) with XCD-batch affinity.
// Per 2-row iteration: 28 x 1KB global_load_lds chunks (7 per wave) into a
// ping-pong LDS buffer; counted s_waitcnt vmcnt(7) keeps the next rows'
// DMA in flight across compute. Zero VGPRs needed for gathered data.
// ---------------------------------------------------------------------------
__global__ __launch_bounds__(256) void agg_out(const float* __restrict__ v,
                                               const int* __restrict__ delays,
                                               const float* __restrict__ probs,
                                               float* __restrict__ out){
  const int bid = blockIdx.x;             // 2048
  const int xcd = bid & 7;
  const int j0  = bid >> 3;               // 0..255
  const int b   = (xcd << 1) + (j0 >> 7);
  const int tbase = (j0 & 127) << 4;      // 16 contiguous rows
  const int tid = threadIdx.x;
  const int wid = tid >> 6;
  const int lane = tid & 63;
  __shared__ float buf[2][28 * 256];      // 2 x 28 KB (28 chunks x 1 KB)
  __shared__ float psh[TK];
  __shared__ int dsh[TK];
  if (tid < TK){
    psh[tid] = probs[b * TK + tid];
    dsh[tid] = delays[b * TK + tid];
  }
  __syncthreads();

  const char* vbytes = (const char*)v;
  const size_t brow = ((size_t)b) << 11;

  // issue the 28 chunks of iteration s into buf[cur]: chunk c handled by
  // wave c/7; c = row2*14 + k*2 + h  (row2 in {0,1}, stream k<7, half h)
#define AGG_STAGE(s, cur)                                                     \
  {                                                                           \
    const int t0_ = tbase + ((s) << 1);                                       \
    _Pragma("unroll")                                                         \
    for (int i_ = 0; i_ < 7; ++i_){                                           \
      const int c_ = wid * 7 + i_;                                            \
      const int row2_ = (c_ >= 14) ? 1 : 0;                                   \
      const int rem_ = c_ - row2_ * 14;                                       \
      const int k_ = rem_ >> 1, h_ = rem_ & 1;                                \
      const int ts_ = (t0_ + row2_ + dsh[k_]) & (LL - 1);                     \
      const char* g_ = vbytes + (((size_t)(brow + ts_)) << 11) +              \
                       (h_ << 10) + (lane << 4);                              \
      char* lp_ = (char*)&buf[cur][0] + c_ * 1024;                            \
      __builtin_amdgcn_global_load_lds(                                       \
          (const __attribute__((address_space(1))) void*)g_,                  \
          (__attribute__((address_space(3))) void*)lp_, 16, 0, 0);            \
    }                                                                         \
  }

  AGG_STAGE(0, 0);
  const int row_off = tid >> 7;           // 0..1
  const int slot = tid & 127;             // float4 slot in row
  const int lbase_off = row_off * 14 + (slot >> 6);   // chunk base for k=0
  const int lbyte = (slot & 63) << 4;
#pragma unroll
  for (int s = 0; s < 8; ++s){
    const int cur = s & 1;
    if (s < 7){
      AGG_STAGE(s + 1, cur ^ 1);
      asm volatile("s_waitcnt vmcnt(7)" ::: "memory");
    } else {
      asm volatile("s_waitcnt vmcnt(0)" ::: "memory");
    }
    __syncthreads();                       // buf[cur] fully staged (all waves)
    f32x4v acc = {0.f, 0.f, 0.f, 0.f};
#pragma unroll
    for (int k = 0; k < TK; ++k){
      const f32x4v xv = *reinterpret_cast<const f32x4v*>(
          (const char*)&buf[cur][0] + (lbase_off + (k << 1)) * 1024 + lbyte);
      acc += xv * psh[k];
    }
    const int t = tbase + (s << 1) + row_off;
    f32x4v* o = reinterpret_cast<f32x4v*>(out + ((brow + t) << 9)) + slot;
    __builtin_nontemporal_store(acc, o);
    __syncthreads();                       // reads done before buf[cur] reuse
  }
#undef AGG_STAGE
}

// ---------------------------------------------------------------------------
extern "C" void kernel_launch(void* const* d_in, const int* in_sizes, int n_in,
                              void* d_out, int out_size, void* d_ws, size_t ws_size,
                              hipStream_t stream){
  const float* q = (const float*)d_in[0];
  const float* k = (const float*)d_in[1];
  const float* v = (const float*)d_in[2];
  float* out = (float*)d_out;

  char* ws = (char*)d_ws;
  const size_t Z_BYTES  = (size_t)BB * CC * LL * sizeof(__half2);   // 67.1 MB
  const size_t PP_BYTES = (size_t)BB * NG * PSTR * sizeof(float2);  // 17.3 MB
  const size_t P_BYTES  = (size_t)BB * LL * sizeof(float2);         // 256 KB
  __half2* zbuf = (__half2*)ws;
  float2* Ppart = (float2*)(ws + Z_BYTES);
  float2* Pbuf  = (float2*)(ws + Z_BYTES + PP_BYTES);
  int* delays = (int*)(ws + Z_BYTES + PP_BYTES + P_BYTES);
  float* probs = (float*)(ws + Z_BYTES + PP_BYTES + P_BYTES + 1024);

  hipLaunchKernelGGL(transpose_pack, dim3(BB * 32 * 8), dim3(256), 0, stream, q, k, zbuf);
  hipLaunchKernelGGL(fft_fwd, dim3(BB * NG), dim3(256), 0, stream, zbuf, Ppart);
  hipLaunchKernelGGL(reduce_P, dim3((BB * LL) / 256), dim3(256), 0, stream, Ppart, Pbuf);
  hipLaunchKernelGGL(fft_inv_topk, dim3(BB), dim3(256), 0, stream, Pbuf, delays, probs);
  hipLaunchKernelGGL(agg_out, dim3(2048), dim3(256), 0, stream,
                     v, delays, probs, out);
}

// Round 16
// 118.242 us; speedup vs baseline: 1.1283x; 1.0419x over previous
//
#include <hip/hip_runtime.h>
#include <hip/hip_fp16.h>
#include <cstdint>
#include <cstddef>

#define BB 16
#define LL 2048
#define CC 512   // H*E
#define TK 7     // int(log(2048)) = 7
#define PDC(a) ((a) + ((a) >> 4))   // cf-unit LDS pad: +1 cf per 16
#define PSTR 1056                   // Ppart per-group stride (1025 used)
#define NG 128                      // fwd groups per batch (4 channels each)

typedef float2 cf;
typedef __attribute__((ext_vector_type(4))) float f32x4v;

__device__ inline cf cadd(cf a, cf b){ return make_float2(a.x + b.x, a.y + b.y); }
__device__ inline cf csub(cf a, cf b){ return make_float2(a.x - b.x, a.y - b.y); }
__device__ inline cf cmul(cf a, cf b){ return make_float2(a.x*b.x - a.y*b.y, a.x*b.y + a.y*b.x); }

// S*i*z : forward S=-1 -> (z.y, -z.x); inverse S=+1 -> (-z.y, z.x)
template<int S> __device__ inline cf crot(cf z){
  return (S < 0) ? make_float2(z.y, -z.x) : make_float2(-z.y, z.x);
}

template<int S> __device__ inline void dft4(cf* x){
  const cf t0 = cadd(x[0], x[2]), t1 = csub(x[0], x[2]);
  const cf t2 = cadd(x[1], x[3]), t3 = csub(x[1], x[3]);
  const cf r = crot<S>(t3);
  x[0] = cadd(t0, t2); x[2] = csub(t0, t2);
  x[1] = cadd(t1, r);  x[3] = csub(t1, r);
}

template<int S> __device__ inline void dft8(cf* x){
  cf e[4] = { x[0], x[2], x[4], x[6] };
  cf o[4] = { x[1], x[3], x[5], x[7] };
  dft4<S>(e); dft4<S>(o);
  const float H = 0.70710678118654752440f;
  o[1] = cmul(o[1], make_float2(H, (float)S * H));
  o[2] = crot<S>(o[2]);
  o[3] = cmul(o[3], make_float2(-H, (float)S * H));
  x[0] = cadd(e[0], o[0]); x[4] = csub(e[0], o[0]);
  x[1] = cadd(e[1], o[1]); x[5] = csub(e[1], o[1]);
  x[2] = cadd(e[2], o[2]); x[6] = csub(e[2], o[2]);
  x[3] = cadd(e[3], o[3]); x[7] = csub(e[3], o[3]);
}

struct Tw { cf w2[7], w3[7], w4a[3], w4b[3]; };

template<int S>
__device__ inline void make_tw(int tid, Tw& T){
  const float base = (float)S * 6.283185307179586f / 2048.0f;
  const int j7 = tid & 7, j63 = tid & 63;
#pragma unroll
  for (int i = 0; i < 7; ++i){
    float s, c;
    __sincosf(base * (float)(32 * (i + 1) * j7), &s, &c);  T.w2[i] = make_float2(c, s);
    __sincosf(base * (float)( 4 * (i + 1) * j63), &s, &c); T.w3[i] = make_float2(c, s);
  }
#pragma unroll
  for (int i = 0; i < 3; ++i){
    float s, c;
    __sincosf(base * (float)((i + 1) * tid), &s, &c);         T.w4a[i] = make_float2(c, s);
    __sincosf(base * (float)((i + 1) * (tid + 256)), &s, &c); T.w4b[i] = make_float2(c, s);
  }
}

// Stages 1-3 with DUAL buffers (used by fft_inv_topk only).
template<int S>
__device__ inline void fft_s123(cf* Bc, cf* Cc, cf* x, const Tw& T, int tid){
  dft8<S>(x);
#pragma unroll
  for (int t = 0; t < 8; ++t) Bc[PDC((tid << 3) + t)] = x[t];
  __syncthreads();
  {
    cf y[8];
#pragma unroll
    for (int t = 0; t < 8; ++t) y[t] = Bc[PDC(tid + (t << 8))];
#pragma unroll
    for (int t = 1; t < 8; ++t) y[t] = cmul(y[t], T.w2[t - 1]);
    dft8<S>(y);
    const int base = ((tid >> 3) << 6) + (tid & 7);
#pragma unroll
    for (int t = 0; t < 8; ++t) Cc[PDC(base + (t << 3))] = y[t];
  }
  __syncthreads();
  {
    cf y[8];
#pragma unroll
    for (int t = 0; t < 8; ++t) y[t] = Cc[PDC(tid + (t << 8))];
#pragma unroll
    for (int t = 1; t < 8; ++t) y[t] = cmul(y[t], T.w3[t - 1]);
    dft8<S>(y);
    const int base = ((tid >> 6) << 9) + (tid & 63);
#pragma unroll
    for (int t = 0; t < 8; ++t) Bc[PDC(base + (t << 6))] = y[t];
  }
  __syncthreads();
}

// ---------------------------------------------------------------------------
// Phase 1: z[b][c][t] = half2(q[b][t][c], k[b][t][c])  (64x64 fp16 LDS tile)
// ---------------------------------------------------------------------------
__global__ __launch_bounds__(256) void transpose_pack(const float* __restrict__ q,
                                                      const float* __restrict__ k,
                                                      __half2* __restrict__ z){
  int bid = blockIdx.x;
  const int tt = bid & 31; bid >>= 5;
  const int ct = bid & 7;  bid >>= 3;
  const int b = bid;
  const int t0 = tt << 6, c0 = ct << 6;
  __shared__ __half2 T[64][69];   // [t][c], pad 69 to break bank strides
  const int tid = threadIdx.x;
  const size_t inbase = ((size_t)b * LL + t0) * CC + c0;
  const int c4 = (tid & 15) << 2;
  f32x4v a[4], e[4];
#pragma unroll
  for (int p2 = 0; p2 < 4; ++p2){
    const int row = (p2 << 4) + (tid >> 4);
    a[p2] = __builtin_nontemporal_load(
        reinterpret_cast<const f32x4v*>(q + inbase + (size_t)row * CC + c4));
    e[p2] = __builtin_nontemporal_load(
        reinterpret_cast<const f32x4v*>(k + inbase + (size_t)row * CC + c4));
  }
#pragma unroll
  for (int p2 = 0; p2 < 4; ++p2){
    const int row = (p2 << 4) + (tid >> 4);
    T[row][c4 + 0] = __floats2half2_rn(a[p2][0], e[p2][0]);
    T[row][c4 + 1] = __floats2half2_rn(a[p2][1], e[p2][1]);
    T[row][c4 + 2] = __floats2half2_rn(a[p2][2], e[p2][2]);
    T[row][c4 + 3] = __floats2half2_rn(a[p2][3], e[p2][3]);
  }
  __syncthreads();
  const size_t outbase = ((size_t)b * CC + c0) * LL + (size_t)t0;
#pragma unroll
  for (int it = 0; it < 4; ++it){
    const int idx = (it << 8) + tid;
    const int c = idx >> 4;                 // c_local 0..63
    const int t4 = (idx & 15) << 2;         // t_local base (x4)
    const __half2 u0 = T[t4 + 0][c], u1 = T[t4 + 1][c];
    const __half2 u2 = T[t4 + 2][c], u3 = T[t4 + 3][c];
    uint4 w;
    w.x = *reinterpret_cast<const uint*>(&u0);
    w.y = *reinterpret_cast<const uint*>(&u1);
    w.z = *reinterpret_cast<const uint*>(&u2);
    w.w = *reinterpret_cast<const uint*>(&u3);
    *reinterpret_cast<uint4*>(&z[outbase + (size_t)c * LL + t4]) = w;
  }
}

// ---------------------------------------------------------------------------
// Phase 2: per (b, group of 4 channels): forward FFT, single 17.4 KB LDS
// buffer, 8 blocks/CU. P[f] for f in [0,1024] (Hermitian rest in reduce_P).
// ---------------------------------------------------------------------------
__global__ __launch_bounds__(256) void fft_fwd(const __half2* __restrict__ z,
                                               float2* __restrict__ Ppart){
  int bid = blockIdx.x;
  const int g = bid & (NG - 1); const int b = bid >> 7;
  const int tid = threadIdx.x;
  __shared__ cf B[2176];
  Tw T; make_tw<-1>(tid, T);
  const __half2* zg = z + (((size_t)b * CC + (size_t)g * 4) << 11);
  float accRe[4] = {0,0,0,0};
  float accIm[4] = {0,0,0,0};
  float acc1024 = 0.f;
  __half2 h[8];
#pragma unroll
  for (int t = 0; t < 8; ++t) h[t] = zg[tid + (t << 8)];
  for (int ch = 0; ch < 4; ++ch){
    cf x[8];
#pragma unroll
    for (int t = 0; t < 8; ++t) x[t] = __half22float2(h[t]);
    if (ch < 3){
      const __half2* zn = zg + ((size_t)(ch + 1) << 11);
#pragma unroll
      for (int t = 0; t < 8; ++t) h[t] = zn[tid + (t << 8)];
    }
    // stage 1 (regs)
    dft8<-1>(x);
    __syncthreads();                       // prior combine reads of B done
#pragma unroll
    for (int t = 0; t < 8; ++t) B[PDC((tid << 3) + t)] = x[t];
    __syncthreads();
    // stage 2
    cf y[8];
#pragma unroll
    for (int t = 0; t < 8; ++t) y[t] = B[PDC(tid + (t << 8))];
#pragma unroll
    for (int t = 1; t < 8; ++t) y[t] = cmul(y[t], T.w2[t - 1]);
    dft8<-1>(y);
    __syncthreads();
    {
      const int base = ((tid >> 3) << 6) + (tid & 7);
#pragma unroll
      for (int t = 0; t < 8; ++t) B[PDC(base + (t << 3))] = y[t];
    }
    __syncthreads();
    // stage 3
#pragma unroll
    for (int t = 0; t < 8; ++t) y[t] = B[PDC(tid + (t << 8))];
#pragma unroll
    for (int t = 1; t < 8; ++t) y[t] = cmul(y[t], T.w3[t - 1]);
    dft8<-1>(y);
    __syncthreads();
    {
      const int base = ((tid >> 6) << 9) + (tid & 63);
#pragma unroll
      for (int t = 0; t < 8; ++t) B[PDC(base + (t << 6))] = y[t];
    }
    __syncthreads();
    // stage 4 (in-place: reads/writes only this thread's slots j+512t)
    cf y0[4], y1[4];
#pragma unroll
    for (int t = 0; t < 4; ++t) y0[t] = B[PDC(tid + (t << 9))];
#pragma unroll
    for (int t = 0; t < 4; ++t) y1[t] = B[PDC(tid + 256 + (t << 9))];
#pragma unroll
    for (int t = 1; t < 4; ++t){
      y0[t] = cmul(y0[t], T.w4a[t - 1]);
      y1[t] = cmul(y1[t], T.w4b[t - 1]);
    }
    dft4<-1>(y0); dft4<-1>(y1);
#pragma unroll
    for (int t = 0; t < 4; ++t) B[PDC(tid + (t << 9))] = y0[t];
#pragma unroll
    for (int t = 0; t < 4; ++t) B[PDC(tid + 256 + (t << 9))] = y1[t];
    __syncthreads();
    // combine for f = tid + 256r, r<4: A = own regs, Bv = B[2048-f]
    const cf Areg[4] = { y0[0], y1[0], y0[1], y1[1] };
#pragma unroll
    for (int r = 0; r < 4; ++r){
      const int f = tid + (r << 8);
      const int p = (2048 - f) & 2047;
      const cf A = Areg[r];
      const cf Bv = B[PDC(p)];
      accRe[r] += 0.5f  * (Bv.y * A.x + Bv.x * A.y);
      accIm[r] += 0.25f * (A.x * A.x + A.y * A.y - Bv.x * Bv.x - Bv.y * Bv.y);
    }
    if (tid == 0){
      const cf A = y0[2];   // f = 1024, self-mirror: Re = Ar*Ai, Im = 0
      acc1024 += A.x * A.y;
    }
  }
  float2* pp = Ppart + ((size_t)b * NG + g) * PSTR;
#pragma unroll
  for (int r = 0; r < 4; ++r)
    pp[tid + (r << 8)] = make_float2(accRe[r], accIm[r]);
  if (tid == 0) pp[1024] = make_float2(acc1024, 0.f);
}

// ---------------------------------------------------------------------------
// Phase 2b: P[b,f] = sum_g Ppart[b,g,min(f,2048-f)], conj for f>1024.
// ---------------------------------------------------------------------------
__global__ __launch_bounds__(256) void reduce_P(const float2* __restrict__ Ppart,
                                                float2* __restrict__ P){
  const int gid = blockIdx.x * 256 + threadIdx.x;  // 0..32767
  const int b = gid >> 11, f = gid & 2047;
  const int src = (f <= 1024) ? f : 2048 - f;
  const float sgn = (f <= 1024) ? 1.f : -1.f;
  float sr = 0.f, si = 0.f;
#pragma unroll 8
  for (int g = 0; g < NG; ++g){
    const float2 v = Ppart[((size_t)b * NG + g) * PSTR + src];
    sr += v.x; si += v.y;
  }
  P[((size_t)b << 11) + f] = make_float2(sr, sgn * si);
}

// ---------------------------------------------------------------------------
// Phase 3: per b: inverse FFT of P, scale -> mv; fused top-7 + softmax.
// ---------------------------------------------------------------------------
__global__ __launch_bounds__(256) void fft_inv_topk(const float2* __restrict__ P,
                                                    int* __restrict__ delays,
                                                    float* __restrict__ probs){
  const int b = blockIdx.x;
  const int tid = threadIdx.x;
  __shared__ cf Bc[2176];
  __shared__ cf Cc[2176];
  __shared__ float vals[2048];
  __shared__ float rv[256]; __shared__ int ri[256];
  __shared__ float wsel[TK]; __shared__ int dsel[TK];
  Tw T; make_tw<1>(tid, T);
  cf x[8];
#pragma unroll
  for (int t = 0; t < 8; ++t) x[t] = P[((size_t)b << 11) + tid + (t << 8)];
  fft_s123<1>(Bc, Cc, x, T, tid);
  const float scale = 1.0f / (2048.0f * 512.0f);
  { // stage 4 in regs; write vals[j + 512t] directly
#pragma unroll
    for (int hh = 0; hh < 2; ++hh){
      const int j = tid + (hh << 8);
      cf y[4];
#pragma unroll
      for (int t = 0; t < 4; ++t) y[t] = Bc[PDC(j + (t << 9))];
      const cf* w = hh ? T.w4b : T.w4a;
#pragma unroll
      for (int t = 1; t < 4; ++t) y[t] = cmul(y[t], w[t - 1]);
      dft4<1>(y);
#pragma unroll
      for (int t = 0; t < 4; ++t) vals[j + (t << 9)] = y[t].x * scale;
    }
  }
  __syncthreads();
  for (int kk = 0; kk < TK; ++kk){
    float best = -1e30f; int bi = LL;
    for (int i = tid; i < LL; i += 256){
      const float xv = vals[i];
      if (xv > best){ best = xv; bi = i; }
    }
    rv[tid] = best; ri[tid] = bi;
    __syncthreads();
    for (int s = 128; s > 0; s >>= 1){
      if (tid < s){
        const float ov = rv[tid + s]; const int oi = ri[tid + s];
        if (ov > rv[tid] || (ov == rv[tid] && oi < ri[tid])){ rv[tid] = ov; ri[tid] = oi; }
      }
      __syncthreads();
    }
    if (tid == 0){ wsel[kk] = rv[0]; dsel[kk] = ri[0]; vals[ri[0]] = -1e30f; }
    __syncthreads();
  }
  if (tid == 0){
    const float m = wsel[0];
    float e[TK], ssum = 0.f;
#pragma unroll
    for (int i = 0; i < TK; ++i){ e[i] = expf(wsel[i] - m); ssum += e[i]; }
    const float inv = 1.0f / ssum;
#pragma unroll
    for (int i = 0; i < TK; ++i){
      probs[b * TK + i] = e[i] * inv;
      delays[b * TK + i] = dsel[i];
    }
  }
}

// ---------------------------------------------------------------------------
// Phase 4 (register ping-pong, contiguous rows): out[b,t,:] = sum_k p_k * v.
// 2048 blocks = (xcd, 16-contiguous-row span); one batch per block.
// Iteration s computes 2 rows while the next 2 rows' 7 gather loads are in
// flight in the other named register set. The asm compiler barrier prevents
// hipcc from sinking the issued loads below the FMA chain (the round-14
// failure: VGPR collapsed to 32 = serialized loads).
// ---------------------------------------------------------------------------
__global__ __launch_bounds__(256) void agg_out(const float* __restrict__ v,
                                               const int* __restrict__ delays,
                                               const float* __restrict__ probs,
                                               float* __restrict__ out){
  const int bid = blockIdx.x;             // 2048
  const int xcd = bid & 7;
  const int j0  = bid >> 3;               // 0..255
  const int b   = (xcd << 1) + (j0 >> 7);
  const int tbase = (j0 & 127) << 4;      // 16 contiguous rows
  const int tid = threadIdx.x;
  const int row_off = tid >> 7;           // 0..1
  const int slot = tid & 127;             // float4 slot in row
  float p[TK]; int d[TK];
#pragma unroll
  for (int k = 0; k < TK; ++k){
    p[k] = probs[b * TK + k];
    d[k] = delays[b * TK + k];
  }
  const f32x4v* v4 = reinterpret_cast<const f32x4v*>(v);
  const size_t brow = ((size_t)b) << 11;
  f32x4v A[TK], Bv[TK];

#define AGG_ISSUE(s, X)                                                       \
  {                                                                           \
    const int t_ = tbase + ((s) << 1) + row_off;                              \
    _Pragma("unroll")                                                         \
    for (int k = 0; k < TK; ++k){                                             \
      const int src_ = (t_ + d[k]) & (LL - 1);                                \
      X[k] = v4[((brow + src_) << 7) + slot];                                 \
    }                                                                         \
  }

  AGG_ISSUE(0, A);
#pragma unroll
  for (int s = 0; s < 8; ++s){
    if (s < 7){
      if (s & 1){ AGG_ISSUE(s + 1, A); }
      else      { AGG_ISSUE(s + 1, Bv); }
    }
    asm volatile("" ::: "memory");   // pin issued loads above the FMA chain
    f32x4v acc = {0.f, 0.f, 0.f, 0.f};
    if (s & 1){
#pragma unroll
      for (int k = 0; k < TK; ++k) acc += Bv[k] * p[k];
    } else {
#pragma unroll
      for (int k = 0; k < TK; ++k) acc += A[k] * p[k];
    }
    const int t = tbase + (s << 1) + row_off;
    f32x4v* o = reinterpret_cast<f32x4v*>(out) + ((brow + t) << 7) + slot;
    __builtin_nontemporal_store(acc, o);
  }
#undef AGG_ISSUE
}

// ---------------------------------------------------------------------------
extern "C" void kernel_launch(void* const* d_in, const int* in_sizes, int n_in,
                              void* d_out, int out_size, void* d_ws, size_t ws_size,
                              hipStream_t stream){
  const float* q = (const float*)d_in[0];
  const float* k = (const float*)d_in[1];
  const float* v = (const float*)d_in[2];
  float* out = (float*)d_out;

  char* ws = (char*)d_ws;
  const size_t Z_BYTES  = (size_t)BB * CC * LL * sizeof(__half2);   // 67.1 MB
  const size_t PP_BYTES = (size_t)BB * NG * PSTR * sizeof(float2);  // 17.3 MB
  const size_t P_BYTES  = (size_t)BB * LL * sizeof(float2);         // 256 KB
  __half2* zbuf = (__half2*)ws;
  float2* Ppart = (float2*)(ws + Z_BYTES);
  float2* Pbuf  = (float2*)(ws + Z_BYTES + PP_BYTES);
  int* delays = (int*)(ws + Z_BYTES + PP_BYTES + P_BYTES);
  float* probs = (float*)(ws + Z_BYTES + PP_BYTES + P_BYTES + 1024);

  hipLaunchKernelGGL(transpose_pack, dim3(BB * 32 * 8), dim3(256), 0, stream, q, k, zbuf);
  hipLaunchKernelGGL(fft_fwd, dim3(BB * NG), dim3(256), 0, stream, zbuf, Ppart);
  hipLaunchKernelGGL(reduce_P, dim3((BB * LL) / 256), dim3(256), 0, stream, Ppart, Pbuf);
  hipLaunchKernelGGL(fft_inv_topk, dim3(BB), dim3(256), 0, stream, Pbuf, delays, probs);
  hipLaunchKernelGGL(agg_out, dim3(2048), dim3(256), 0, stream,
                     v, delays, probs, out);
}

// Round 17
// 116.344 us; speedup vs baseline: 1.1467x; 1.0163x over previous
//
#include <hip/hip_runtime.h>
#include <hip/hip_fp16.h>
#include <cstdint>
#include <cstddef>

#define BB 16
#define LL 2048
#define CC 512   // H*E
#define TK 7     // int(log(2048)) = 7
#define PDC(a) ((a) + ((a) >> 4))   // cf-unit LDS pad: +1 cf per 16
#define PSTR 1056                   // Ppart per-group stride (1025 used)
#define NG 128                      // fwd groups per batch (4 channels each)

typedef float2 cf;
typedef __attribute__((ext_vector_type(4))) float f32x4v;

__device__ inline cf cadd(cf a, cf b){ return make_float2(a.x + b.x, a.y + b.y); }
__device__ inline cf csub(cf a, cf b){ return make_float2(a.x - b.x, a.y - b.y); }
__device__ inline cf cmul(cf a, cf b){ return make_float2(a.x*b.x - a.y*b.y, a.x*b.y + a.y*b.x); }

// S*i*z : forward S=-1 -> (z.y, -z.x); inverse S=+1 -> (-z.y, z.x)
template<int S> __device__ inline cf crot(cf z){
  return (S < 0) ? make_float2(z.y, -z.x) : make_float2(-z.y, z.x);
}

template<int S> __device__ inline void dft4(cf* x){
  const cf t0 = cadd(x[0], x[2]), t1 = csub(x[0], x[2]);
  const cf t2 = cadd(x[1], x[3]), t3 = csub(x[1], x[3]);
  const cf r = crot<S>(t3);
  x[0] = cadd(t0, t2); x[2] = csub(t0, t2);
  x[1] = cadd(t1, r);  x[3] = csub(t1, r);
}

template<int S> __device__ inline void dft8(cf* x){
  cf e[4] = { x[0], x[2], x[4], x[6] };
  cf o[4] = { x[1], x[3], x[5], x[7] };
  dft4<S>(e); dft4<S>(o);
  const float H = 0.70710678118654752440f;
  o[1] = cmul(o[1], make_float2(H, (float)S * H));
  o[2] = crot<S>(o[2]);
  o[3] = cmul(o[3], make_float2(-H, (float)S * H));
  x[0] = cadd(e[0], o[0]); x[4] = csub(e[0], o[0]);
  x[1] = cadd(e[1], o[1]); x[5] = csub(e[1], o[1]);
  x[2] = cadd(e[2], o[2]); x[6] = csub(e[2], o[2]);
  x[3] = cadd(e[3], o[3]); x[7] = csub(e[3], o[3]);
}

struct Tw { cf w2[7], w3[7], w4a[3], w4b[3]; };

template<int S>
__device__ inline void make_tw(int tid, Tw& T){
  const float base = (float)S * 6.283185307179586f / 2048.0f;
  const int j7 = tid & 7, j63 = tid & 63;
#pragma unroll
  for (int i = 0; i < 7; ++i){
    float s, c;
    __sincosf(base * (float)(32 * (i + 1) * j7), &s, &c);  T.w2[i] = make_float2(c, s);
    __sincosf(base * (float)( 4 * (i + 1) * j63), &s, &c); T.w3[i] = make_float2(c, s);
  }
#pragma unroll
  for (int i = 0; i < 3; ++i){
    float s, c;
    __sincosf(base * (float)((i + 1) * tid), &s, &c);         T.w4a[i] = make_float2(c, s);
    __sincosf(base * (float)((i + 1) * (tid + 256)), &s, &c); T.w4b[i] = make_float2(c, s);
  }
}

// Stages 1-3 with DUAL buffers (used by fft_inv_topk only).
template<int S>
__device__ inline void fft_s123(cf* Bc, cf* Cc, cf* x, const Tw& T, int tid){
  dft8<S>(x);
#pragma unroll
  for (int t = 0; t < 8; ++t) Bc[PDC((tid << 3) + t)] = x[t];
  __syncthreads();
  {
    cf y[8];
#pragma unroll
    for (int t = 0; t < 8; ++t) y[t] = Bc[PDC(tid + (t << 8))];
#pragma unroll
    for (int t = 1; t < 8; ++t) y[t] = cmul(y[t], T.w2[t - 1]);
    dft8<S>(y);
    const int base = ((tid >> 3) << 6) + (tid & 7);
#pragma unroll
    for (int t = 0; t < 8; ++t) Cc[PDC(base + (t << 3))] = y[t];
  }
  __syncthreads();
  {
    cf y[8];
#pragma unroll
    for (int t = 0; t < 8; ++t) y[t] = Cc[PDC(tid + (t << 8))];
#pragma unroll
    for (int t = 1; t < 8; ++t) y[t] = cmul(y[t], T.w3[t - 1]);
    dft8<S>(y);
    const int base = ((tid >> 6) << 9) + (tid & 63);
#pragma unroll
    for (int t = 0; t < 8; ++t) Bc[PDC(base + (t << 6))] = y[t];
  }
  __syncthreads();
}

// ---------------------------------------------------------------------------
// Phase 1: z[b][c][t] = half2(q[b][t][c], k[b][t][c])  (64x64 fp16 LDS tile)
// ---------------------------------------------------------------------------
__global__ __launch_bounds__(256) void transpose_pack(const float* __restrict__ q,
                                                      const float* __restrict__ k,
                                                      __half2* __restrict__ z){
  int bid = blockIdx.x;
  const int tt = bid & 31; bid >>= 5;
  const int ct = bid & 7;  bid >>= 3;
  const int b = bid;
  const int t0 = tt << 6, c0 = ct << 6;
  __shared__ __half2 T[64][69];   // [t][c], pad 69 to break bank strides
  const int tid = threadIdx.x;
  const size_t inbase = ((size_t)b * LL + t0) * CC + c0;
  const int c4 = (tid & 15) << 2;
  f32x4v a[4], e[4];
#pragma unroll
  for (int p2 = 0; p2 < 4; ++p2){
    const int row = (p2 << 4) + (tid >> 4);
    a[p2] = __builtin_nontemporal_load(
        reinterpret_cast<const f32x4v*>(q + inbase + (size_t)row * CC + c4));
    e[p2] = __builtin_nontemporal_load(
        reinterpret_cast<const f32x4v*>(k + inbase + (size_t)row * CC + c4));
  }
#pragma unroll
  for (int p2 = 0; p2 < 4; ++p2){
    const int row = (p2 << 4) + (tid >> 4);
    T[row][c4 + 0] = __floats2half2_rn(a[p2][0], e[p2][0]);
    T[row][c4 + 1] = __floats2half2_rn(a[p2][1], e[p2][1]);
    T[row][c4 + 2] = __floats2half2_rn(a[p2][2], e[p2][2]);
    T[row][c4 + 3] = __floats2half2_rn(a[p2][3], e[p2][3]);
  }
  __syncthreads();
  const size_t outbase = ((size_t)b * CC + c0) * LL + (size_t)t0;
#pragma unroll
  for (int it = 0; it < 4; ++it){
    const int idx = (it << 8) + tid;
    const int c = idx >> 4;                 // c_local 0..63
    const int t4 = (idx & 15) << 2;         // t_local base (x4)
    const __half2 u0 = T[t4 + 0][c], u1 = T[t4 + 1][c];
    const __half2 u2 = T[t4 + 2][c], u3 = T[t4 + 3][c];
    uint4 w;
    w.x = *reinterpret_cast<const uint*>(&u0);
    w.y = *reinterpret_cast<const uint*>(&u1);
    w.z = *reinterpret_cast<const uint*>(&u2);
    w.w = *reinterpret_cast<const uint*>(&u3);
    *reinterpret_cast<uint4*>(&z[outbase + (size_t)c * LL + t4]) = w;
  }
}

// ---------------------------------------------------------------------------
// Phase 2: per (b, group of 4 channels): forward FFT, single 17.4 KB LDS
// buffer, 8 blocks/CU. P[f] for f in [0,1024] (Hermitian rest in reduce_P).
// ---------------------------------------------------------------------------
__global__ __launch_bounds__(256) void fft_fwd(const __half2* __restrict__ z,
                                               float2* __restrict__ Ppart){
  int bid = blockIdx.x;
  const int g = bid & (NG - 1); const int b = bid >> 7;
  const int tid = threadIdx.x;
  __shared__ cf B[2176];
  Tw T; make_tw<-1>(tid, T);
  const __half2* zg = z + (((size_t)b * CC + (size_t)g * 4) << 11);
  float accRe[4] = {0,0,0,0};
  float accIm[4] = {0,0,0,0};
  float acc1024 = 0.f;
  __half2 h[8];
#pragma unroll
  for (int t = 0; t < 8; ++t) h[t] = zg[tid + (t << 8)];
  for (int ch = 0; ch < 4; ++ch){
    cf x[8];
#pragma unroll
    for (int t = 0; t < 8; ++t) x[t] = __half22float2(h[t]);
    if (ch < 3){
      const __half2* zn = zg + ((size_t)(ch + 1) << 11);
#pragma unroll
      for (int t = 0; t < 8; ++t) h[t] = zn[tid + (t << 8)];
    }
    // stage 1 (regs)
    dft8<-1>(x);
    __syncthreads();                       // prior combine reads of B done
#pragma unroll
    for (int t = 0; t < 8; ++t) B[PDC((tid << 3) + t)] = x[t];
    __syncthreads();
    // stage 2
    cf y[8];
#pragma unroll
    for (int t = 0; t < 8; ++t) y[t] = B[PDC(tid + (t << 8))];
#pragma unroll
    for (int t = 1; t < 8; ++t) y[t] = cmul(y[t], T.w2[t - 1]);
    dft8<-1>(y);
    __syncthreads();
    {
      const int base = ((tid >> 3) << 6) + (tid & 7);
#pragma unroll
      for (int t = 0; t < 8; ++t) B[PDC(base + (t << 3))] = y[t];
    }
    __syncthreads();
    // stage 3
#pragma unroll
    for (int t = 0; t < 8; ++t) y[t] = B[PDC(tid + (t << 8))];
#pragma unroll
    for (int t = 1; t < 8; ++t) y[t] = cmul(y[t], T.w3[t - 1]);
    dft8<-1>(y);
    __syncthreads();
    {
      const int base = ((tid >> 6) << 9) + (tid & 63);
#pragma unroll
      for (int t = 0; t < 8; ++t) B[PDC(base + (t << 6))] = y[t];
    }
    __syncthreads();
    // stage 4 (in-place: reads/writes only this thread's slots j+512t)
    cf y0[4], y1[4];
#pragma unroll
    for (int t = 0; t < 4; ++t) y0[t] = B[PDC(tid + (t << 9))];
#pragma unroll
    for (int t = 0; t < 4; ++t) y1[t] = B[PDC(tid + 256 + (t << 9))];
#pragma unroll
    for (int t = 1; t < 4; ++t){
      y0[t] = cmul(y0[t], T.w4a[t - 1]);
      y1[t] = cmul(y1[t], T.w4b[t - 1]);
    }
    dft4<-1>(y0); dft4<-1>(y1);
#pragma unroll
    for (int t = 0; t < 4; ++t) B[PDC(tid + (t << 9))] = y0[t];
#pragma unroll
    for (int t = 0; t < 4; ++t) B[PDC(tid + 256 + (t << 9))] = y1[t];
    __syncthreads();
    // combine for f = tid + 256r, r<4: A = own regs, Bv = B[2048-f]
    const cf Areg[4] = { y0[0], y1[0], y0[1], y1[1] };
#pragma unroll
    for (int r = 0; r < 4; ++r){
      const int f = tid + (r << 8);
      const int p = (2048 - f) & 2047;
      const cf A = Areg[r];
      const cf Bv = B[PDC(p)];
      accRe[r] += 0.5f  * (Bv.y * A.x + Bv.x * A.y);
      accIm[r] += 0.25f * (A.x * A.x + A.y * A.y - Bv.x * Bv.x - Bv.y * Bv.y);
    }
    if (tid == 0){
      const cf A = y0[2];   // f = 1024, self-mirror: Re = Ar*Ai, Im = 0
      acc1024 += A.x * A.y;
    }
  }
  float2* pp = Ppart + ((size_t)b * NG + g) * PSTR;
#pragma unroll
  for (int r = 0; r < 4; ++r)
    pp[tid + (r << 8)] = make_float2(accRe[r], accIm[r]);
  if (tid == 0) pp[1024] = make_float2(acc1024, 0.f);
}

// ---------------------------------------------------------------------------
// Phase 2b: P[b,f] = sum_g Ppart[b,g,min(f,2048-f)], conj for f>1024.
// ---------------------------------------------------------------------------
__global__ __launch_bounds__(256) void reduce_P(const float2* __restrict__ Ppart,
                                                float2* __restrict__ P){
  const int gid = blockIdx.x * 256 + threadIdx.x;  // 0..32767
  const int b = gid >> 11, f = gid & 2047;
  const int src = (f <= 1024) ? f : 2048 - f;
  const float sgn = (f <= 1024) ? 1.f : -1.f;
  float sr = 0.f, si = 0.f;
#pragma unroll 8
  for (int g = 0; g < NG; ++g){
    const float2 v = Ppart[((size_t)b * NG + g) * PSTR + src];
    sr += v.x; si += v.y;
  }
  P[((size_t)b << 11) + f] = make_float2(sr, sgn * si);
}

// ---------------------------------------------------------------------------
// Phase 3: per b: inverse FFT of P, scale -> mv; fused top-7 + softmax.
// ---------------------------------------------------------------------------
__global__ __launch_bounds__(256) void fft_inv_topk(const float2* __restrict__ P,
                                                    int* __restrict__ delays,
                                                    float* __restrict__ probs){
  const int b = blockIdx.x;
  const int tid = threadIdx.x;
  __shared__ cf Bc[2176];
  __shared__ cf Cc[2176];
  __shared__ float vals[2048];
  __shared__ float rv[256]; __shared__ int ri[256];
  __shared__ float wsel[TK]; __shared__ int dsel[TK];
  Tw T; make_tw<1>(tid, T);
  cf x[8];
#pragma unroll
  for (int t = 0; t < 8; ++t) x[t] = P[((size_t)b << 11) + tid + (t << 8)];
  fft_s123<1>(Bc, Cc, x, T, tid);
  const float scale = 1.0f / (2048.0f * 512.0f);
  { // stage 4 in regs; write vals[j + 512t] directly
#pragma unroll
    for (int hh = 0; hh < 2; ++hh){
      const int j = tid + (hh << 8);
      cf y[4];
#pragma unroll
      for (int t = 0; t < 4; ++t) y[t] = Bc[PDC(j + (t << 9))];
      const cf* w = hh ? T.w4b : T.w4a;
#pragma unroll
      for (int t = 1; t < 4; ++t) y[t] = cmul(y[t], w[t - 1]);
      dft4<1>(y);
#pragma unroll
      for (int t = 0; t < 4; ++t) vals[j + (t << 9)] = y[t].x * scale;
    }
  }
  __syncthreads();
  for (int kk = 0; kk < TK; ++kk){
    float best = -1e30f; int bi = LL;
    for (int i = tid; i < LL; i += 256){
      const float xv = vals[i];
      if (xv > best){ best = xv; bi = i; }
    }
    rv[tid] = best; ri[tid] = bi;
    __syncthreads();
    for (int s = 128; s > 0; s >>= 1){
      if (tid < s){
        const float ov = rv[tid + s]; const int oi = ri[tid + s];
        if (ov > rv[tid] || (ov == rv[tid] && oi < ri[tid])){ rv[tid] = ov; ri[tid] = oi; }
      }
      __syncthreads();
    }
    if (tid == 0){ wsel[kk] = rv[0]; dsel[kk] = ri[0]; vals[ri[0]] = -1e30f; }
    __syncthreads();
  }
  if (tid == 0){
    const float m = wsel[0];
    float e[TK], ssum = 0.f;
#pragma unroll
    for (int i = 0; i < TK; ++i){ e[i] = expf(wsel[i] - m); ssum += e[i]; }
    const float inv = 1.0f / ssum;
#pragma unroll
    for (int i = 0; i < TK; ++i){
      probs[b * TK + i] = e[i] * inv;
      delays[b * TK + i] = dsel[i];
    }
  }
}

// ---------------------------------------------------------------------------
// Phase 4: out[b,t,:] = sum_k probs[b,k] * v[b,(t+delay[b,k])%L,:]
// r10's best-measured version: XCD-aware batch swizzle (each XCD owns 2
// whole batches; v[b]=4.2MB ~ L2), 4 rows/block, 2 float4/thread, NT stores.
// agg floor ~47us is the d_out write-path cap (67MB @ ~1.4TB/s) — 7
// structural variants all pinned there.
// ---------------------------------------------------------------------------
__global__ __launch_bounds__(256) void agg_out(const float* __restrict__ v,
                                               const int* __restrict__ delays,
                                               const float* __restrict__ probs,
                                               float* __restrict__ out){
  const int bid = blockIdx.x;
  const int xcd = bid & 7;
  const int w = bid >> 3;
  const int b = (xcd << 1) + (w >> 9);
  const int local = w & 511;
  const int tid = threadIdx.x;
  const int t = (local << 2) + (tid >> 6);   // 4 rows per block
  const int i0 = tid & 63;                   // float4 slots i0 and i0+64
  const int row = (b << 11) + t;
  f32x4v acc0 = {0.f, 0.f, 0.f, 0.f};
  f32x4v acc1 = {0.f, 0.f, 0.f, 0.f};
#pragma unroll
  for (int kk = 0; kk < TK; ++kk){
    const int d = delays[b * TK + kk];
    const float p = probs[b * TK + kk];
    const int srcr = (t + d) & (LL - 1);
    const size_t base = (size_t)((b << 11) + srcr) * 128;
    const f32x4v x0 = reinterpret_cast<const f32x4v*>(v)[base + i0];
    const f32x4v x1 = reinterpret_cast<const f32x4v*>(v)[base + i0 + 64];
    acc0 += x0 * p;
    acc1 += x1 * p;
  }
  f32x4v* o = reinterpret_cast<f32x4v*>(out) + (size_t)row * 128;
  __builtin_nontemporal_store(acc0, o + i0);
  __builtin_nontemporal_store(acc1, o + i0 + 64);
}

// ---------------------------------------------------------------------------
extern "C" void kernel_launch(void* const* d_in, const int* in_sizes, int n_in,
                              void* d_out, int out_size, void* d_ws, size_t ws_size,
                              hipStream_t stream){
  const float* q = (const float*)d_in[0];
  const float* k = (const float*)d_in[1];
  const float* v = (const float*)d_in[2];
  float* out = (float*)d_out;

  char* ws = (char*)d_ws;
  const size_t Z_BYTES  = (size_t)BB * CC * LL * sizeof(__half2);   // 67.1 MB
  const size_t PP_BYTES = (size_t)BB * NG * PSTR * sizeof(float2);  // 17.3 MB
  const size_t P_BYTES  = (size_t)BB * LL * sizeof(float2);         // 256 KB
  __half2* zbuf = (__half2*)ws;
  float2* Ppart = (float2*)(ws + Z_BYTES);
  float2* Pbuf  = (float2*)(ws + Z_BYTES + PP_BYTES);
  int* delays = (int*)(ws + Z_BYTES + PP_BYTES + P_BYTES);
  float* probs = (float*)(ws + Z_BYTES + PP_BYTES + P_BYTES + 1024);

  hipLaunchKernelGGL(transpose_pack, dim3(BB * 32 * 8), dim3(256), 0, stream, q, k, zbuf);
  hipLaunchKernelGGL(fft_fwd, dim3(BB * NG), dim3(256), 0, stream, zbuf, Ppart);
  hipLaunchKernelGGL(reduce_P, dim3((BB * LL) / 256), dim3(256), 0, stream, Ppart, Pbuf);
  hipLaunchKernelGGL(fft_inv_topk, dim3(BB), dim3(256), 0, stream, Pbuf, delays, probs);
  hipLaunchKernelGGL(agg_out, dim3(BB * 512), dim3(256), 0, stream,
                     v, delays, probs, out);
}

// Round 18
// 115.904 us; speedup vs baseline: 1.1511x; 1.0038x over previous
//
#include <hip/hip_runtime.h>
#include <hip/hip_fp16.h>
#include <cstdint>
#include <cstddef>

#define BB 16
#define LL 2048
#define CC 512   // H*E
#define TK 7     // int(log(2048)) = 7
#define PDC(a) ((a) + ((a) >> 4))   // cf-unit LDS pad: +1 cf per 16
#define PSTR 1056                   // Ppart per-group stride (1025 used)
#define NG 64                       // fwd groups per batch (8 channels each)

typedef float2 cf;
typedef __attribute__((ext_vector_type(4))) float f32x4v;

__device__ inline cf cadd(cf a, cf b){ return make_float2(a.x + b.x, a.y + b.y); }
__device__ inline cf csub(cf a, cf b){ return make_float2(a.x - b.x, a.y - b.y); }
__device__ inline cf cmul(cf a, cf b){ return make_float2(a.x*b.x - a.y*b.y, a.x*b.y + a.y*b.x); }

// S*i*z : forward S=-1 -> (z.y, -z.x); inverse S=+1 -> (-z.y, z.x)
template<int S> __device__ inline cf crot(cf z){
  return (S < 0) ? make_float2(z.y, -z.x) : make_float2(-z.y, z.x);
}

template<int S> __device__ inline void dft4(cf* x){
  const cf t0 = cadd(x[0], x[2]), t1 = csub(x[0], x[2]);
  const cf t2 = cadd(x[1], x[3]), t3 = csub(x[1], x[3]);
  const cf r = crot<S>(t3);
  x[0] = cadd(t0, t2); x[2] = csub(t0, t2);
  x[1] = cadd(t1, r);  x[3] = csub(t1, r);
}

template<int S> __device__ inline void dft8(cf* x){
  cf e[4] = { x[0], x[2], x[4], x[6] };
  cf o[4] = { x[1], x[3], x[5], x[7] };
  dft4<S>(e); dft4<S>(o);
  const float H = 0.70710678118654752440f;
  o[1] = cmul(o[1], make_float2(H, (float)S * H));
  o[2] = crot<S>(o[2]);
  o[3] = cmul(o[3], make_float2(-H, (float)S * H));
  x[0] = cadd(e[0], o[0]); x[4] = csub(e[0], o[0]);
  x[1] = cadd(e[1], o[1]); x[5] = csub(e[1], o[1]);
  x[2] = cadd(e[2], o[2]); x[6] = csub(e[2], o[2]);
  x[3] = cadd(e[3], o[3]); x[7] = csub(e[3], o[3]);
}

struct Tw { cf w2[7], w3[7], w4a[3], w4b[3]; };

template<int S>
__device__ inline void make_tw(int tid, Tw& T){
  const float base = (float)S * 6.283185307179586f / 2048.0f;
  const int j7 = tid & 7, j63 = tid & 63;
#pragma unroll
  for (int i = 0; i < 7; ++i){
    float s, c;
    __sincosf(base * (float)(32 * (i + 1) * j7), &s, &c);  T.w2[i] = make_float2(c, s);
    __sincosf(base * (float)( 4 * (i + 1) * j63), &s, &c); T.w3[i] = make_float2(c, s);
  }
#pragma unroll
  for (int i = 0; i < 3; ++i){
    float s, c;
    __sincosf(base * (float)((i + 1) * tid), &s, &c);         T.w4a[i] = make_float2(c, s);
    __sincosf(base * (float)((i + 1) * (tid + 256)), &s, &c); T.w4b[i] = make_float2(c, s);
  }
}

// Stages 1-3 with dual buffers; ends synced (Bc holds stage-3, Cc free).
template<int S>
__device__ inline void fft_s123(cf* Bc, cf* Cc, cf* x, const Tw& T, int tid){
  dft8<S>(x);
#pragma unroll
  for (int t = 0; t < 8; ++t) Bc[PDC((tid << 3) + t)] = x[t];
  __syncthreads();
  {
    cf y[8];
#pragma unroll
    for (int t = 0; t < 8; ++t) y[t] = Bc[PDC(tid + (t << 8))];
#pragma unroll
    for (int t = 1; t < 8; ++t) y[t] = cmul(y[t], T.w2[t - 1]);
    dft8<S>(y);
    const int base = ((tid >> 3) << 6) + (tid & 7);
#pragma unroll
    for (int t = 0; t < 8; ++t) Cc[PDC(base + (t << 3))] = y[t];
  }
  __syncthreads();
  {
    cf y[8];
#pragma unroll
    for (int t = 0; t < 8; ++t) y[t] = Cc[PDC(tid + (t << 8))];
#pragma unroll
    for (int t = 1; t < 8; ++t) y[t] = cmul(y[t], T.w3[t - 1]);
    dft8<S>(y);
    const int base = ((tid >> 6) << 9) + (tid & 63);
#pragma unroll
    for (int t = 0; t < 8; ++t) Bc[PDC(base + (t << 6))] = y[t];
  }
  __syncthreads();
}

// ---------------------------------------------------------------------------
// Phase 1: z[b][c][t] = half2(q[b][t][c], k[b][t][c])  (64x64 fp16 LDS tile)
// ---------------------------------------------------------------------------
__global__ __launch_bounds__(256) void transpose_pack(const float* __restrict__ q,
                                                      const float* __restrict__ k,
                                                      __half2* __restrict__ z){
  int bid = blockIdx.x;
  const int tt = bid & 31; bid >>= 5;
  const int ct = bid & 7;  bid >>= 3;
  const int b = bid;
  const int t0 = tt << 6, c0 = ct << 6;
  __shared__ __half2 T[64][69];   // [t][c], pad 69 to break bank strides
  const int tid = threadIdx.x;
  const size_t inbase = ((size_t)b * LL + t0) * CC + c0;
  const int c4 = (tid & 15) << 2;
  f32x4v a[4], e[4];
#pragma unroll
  for (int p2 = 0; p2 < 4; ++p2){
    const int row = (p2 << 4) + (tid >> 4);
    a[p2] = __builtin_nontemporal_load(
        reinterpret_cast<const f32x4v*>(q + inbase + (size_t)row * CC + c4));
    e[p2] = __builtin_nontemporal_load(
        reinterpret_cast<const f32x4v*>(k + inbase + (size_t)row * CC + c4));
  }
#pragma unroll
  for (int p2 = 0; p2 < 4; ++p2){
    const int row = (p2 << 4) + (tid >> 4);
    T[row][c4 + 0] = __floats2half2_rn(a[p2][0], e[p2][0]);
    T[row][c4 + 1] = __floats2half2_rn(a[p2][1], e[p2][1]);
    T[row][c4 + 2] = __floats2half2_rn(a[p2][2], e[p2][2]);
    T[row][c4 + 3] = __floats2half2_rn(a[p2][3], e[p2][3]);
  }
  __syncthreads();
  const size_t outbase = ((size_t)b * CC + c0) * LL + (size_t)t0;
#pragma unroll
  for (int it = 0; it < 4; ++it){
    const int idx = (it << 8) + tid;
    const int c = idx >> 4;                 // c_local 0..63
    const int t4 = (idx & 15) << 2;         // t_local base (x4)
    const __half2 u0 = T[t4 + 0][c], u1 = T[t4 + 1][c];
    const __half2 u2 = T[t4 + 2][c], u3 = T[t4 + 3][c];
    uint4 w;
    w.x = *reinterpret_cast<const uint*>(&u0);
    w.y = *reinterpret_cast<const uint*>(&u1);
    w.z = *reinterpret_cast<const uint*>(&u2);
    w.w = *reinterpret_cast<const uint*>(&u3);
    *reinterpret_cast<uint4*>(&z[outbase + (size_t)c * LL + t4]) = w;
  }
}

// ---------------------------------------------------------------------------
// Phase 2: per (b, group of 8 channels): forward FFT of z_c = q_c + i*k_c,
// dual-buffer stages 1-3, stage 4 + combine A-operands in registers.
// P[f] accumulated for f in [0,1024] (Hermitian rest in reduce_P).
// ---------------------------------------------------------------------------
__global__ __launch_bounds__(256) void fft_fwd(const __half2* __restrict__ z,
                                               float2* __restrict__ Ppart){
  int bid = blockIdx.x;
  const int g = bid & (NG - 1); const int b = bid >> 6;
  const int tid = threadIdx.x;
  __shared__ cf Bc[2176];
  __shared__ cf Cc[2176];
  Tw T; make_tw<-1>(tid, T);
  const __half2* zg = z + (((size_t)b * CC + (size_t)g * 8) << 11);
  float accRe[4] = {0,0,0,0};
  float accIm[4] = {0,0,0,0};
  float acc1024 = 0.f;
  __half2 h[8];
#pragma unroll
  for (int t = 0; t < 8; ++t) h[t] = zg[tid + (t << 8)];
  for (int ch = 0; ch < 8; ++ch){
    cf x[8];
#pragma unroll
    for (int t = 0; t < 8; ++t) x[t] = __half22float2(h[t]);
    if (ch < 7){
      const __half2* zn = zg + ((size_t)(ch + 1) << 11);
#pragma unroll
      for (int t = 0; t < 8; ++t) h[t] = zn[tid + (t << 8)];
    }
    fft_s123<-1>(Bc, Cc, x, T, tid);
    // stage 4: radix-4, Ls=512; two butterflies j=tid (y0), j=tid+256 (y1)
    cf y0[4], y1[4];
#pragma unroll
    for (int t = 0; t < 4; ++t) y0[t] = Bc[PDC(tid + (t << 9))];
#pragma unroll
    for (int t = 0; t < 4; ++t) y1[t] = Bc[PDC(tid + 256 + (t << 9))];
#pragma unroll
    for (int t = 1; t < 4; ++t){
      y0[t] = cmul(y0[t], T.w4a[t - 1]);
      y1[t] = cmul(y1[t], T.w4b[t - 1]);
    }
    dft4<-1>(y0); dft4<-1>(y1);
#pragma unroll
    for (int t = 0; t < 4; ++t) Cc[PDC(tid + (t << 9))] = y0[t];
#pragma unroll
    for (int t = 0; t < 4; ++t) Cc[PDC(tid + 256 + (t << 9))] = y1[t];
    __syncthreads();
    // combine for f = tid + 256r, r<4: A = own regs, Bv = Cc[2048-f]
    const cf Areg[4] = { y0[0], y1[0], y0[1], y1[1] };
#pragma unroll
    for (int r = 0; r < 4; ++r){
      const int f = tid + (r << 8);
      const int p = (2048 - f) & 2047;
      const cf A = Areg[r];
      const cf Bv = Cc[PDC(p)];
      accRe[r] += 0.5f  * (Bv.y * A.x + Bv.x * A.y);
      accIm[r] += 0.25f * (A.x * A.x + A.y * A.y - Bv.x * Bv.x - Bv.y * Bv.y);
    }
    if (tid == 0){
      const cf A = y0[2];   // f = 1024, self-mirror: Re = Ar*Ai, Im = 0
      acc1024 += A.x * A.y;
    }
    __syncthreads();        // combine reads of Cc done before next stage-2 write
  }
  float2* pp = Ppart + ((size_t)b * NG + g) * PSTR;
#pragma unroll
  for (int r = 0; r < 4; ++r)
    pp[tid + (r << 8)] = make_float2(accRe[r], accIm[r]);
  if (tid == 0) pp[1024] = make_float2(acc1024, 0.f);
}

// ---------------------------------------------------------------------------
// Phase 2b: P[b,f] = sum_g Ppart[b,g,min(f,2048-f)], conj for f>1024.
// ---------------------------------------------------------------------------
__global__ __launch_bounds__(256) void reduce_P(const float2* __restrict__ Ppart,
                                                float2* __restrict__ P){
  const int gid = blockIdx.x * 256 + threadIdx.x;  // 0..32767
  const int b = gid >> 11, f = gid & 2047;
  const int src = (f <= 1024) ? f : 2048 - f;
  const float sgn = (f <= 1024) ? 1.f : -1.f;
  float sr = 0.f, si = 0.f;
#pragma unroll 8
  for (int g = 0; g < NG; ++g){
    const float2 v = Ppart[((size_t)b * NG + g) * PSTR + src];
    sr += v.x; si += v.y;
  }
  P[((size_t)b << 11) + f] = make_float2(sr, sgn * si);
}

// ---------------------------------------------------------------------------
// Phase 3: per b: inverse FFT of P, scale -> mv; fused top-7 + softmax.
// ---------------------------------------------------------------------------
__global__ __launch_bounds__(256) void fft_inv_topk(const float2* __restrict__ P,
                                                    int* __restrict__ delays,
                                                    float* __restrict__ probs){
  const int b = blockIdx.x;
  const int tid = threadIdx.x;
  __shared__ cf Bc[2176];
  __shared__ cf Cc[2176];
  __shared__ float vals[2048];
  __shared__ float rv[256]; __shared__ int ri[256];
  __shared__ float wsel[TK]; __shared__ int dsel[TK];
  Tw T; make_tw<1>(tid, T);
  cf x[8];
#pragma unroll
  for (int t = 0; t < 8; ++t) x[t] = P[((size_t)b << 11) + tid + (t << 8)];
  fft_s123<1>(Bc, Cc, x, T, tid);
  const float scale = 1.0f / (2048.0f * 512.0f);
  { // stage 4 in regs; write vals[j + 512t] directly
#pragma unroll
    for (int hh = 0; hh < 2; ++hh){
      const int j = tid + (hh << 8);
      cf y[4];
#pragma unroll
      for (int t = 0; t < 4; ++t) y[t] = Bc[PDC(j + (t << 9))];
      const cf* w = hh ? T.w4b : T.w4a;
#pragma unroll
      for (int t = 1; t < 4; ++t) y[t] = cmul(y[t], w[t - 1]);
      dft4<1>(y);
#pragma unroll
      for (int t = 0; t < 4; ++t) vals[j + (t << 9)] = y[t].x * scale;
    }
  }
  __syncthreads();
  for (int kk = 0; kk < TK; ++kk){
    float best = -1e30f; int bi = LL;
    for (int i = tid; i < LL; i += 256){
      const float xv = vals[i];
      if (xv > best){ best = xv; bi = i; }
    }
    rv[tid] = best; ri[tid] = bi;
    __syncthreads();
    for (int s = 128; s > 0; s >>= 1){
      if (tid < s){
        const float ov = rv[tid + s]; const int oi = ri[tid + s];
        if (ov > rv[tid] || (ov == rv[tid] && oi < ri[tid])){ rv[tid] = ov; ri[tid] = oi; }
      }
      __syncthreads();
    }
    if (tid == 0){ wsel[kk] = rv[0]; dsel[kk] = ri[0]; vals[ri[0]] = -1e30f; }
    __syncthreads();
  }
  if (tid == 0){
    const float m = wsel[0];
    float e[TK], ssum = 0.f;
#pragma unroll
    for (int i = 0; i < TK; ++i){ e[i] = expf(wsel[i] - m); ssum += e[i]; }
    const float inv = 1.0f / ssum;
#pragma unroll
    for (int i = 0; i < TK; ++i){
      probs[b * TK + i] = e[i] * inv;
      delays[b * TK + i] = dsel[i];
    }
  }
}

// ---------------------------------------------------------------------------
// Phase 4: out[b,t,:] = sum_k probs[b,k] * v[b,(t+delay[b,k])%L,:]
// Best-measured version (r9/r10): XCD-aware batch swizzle (each XCD owns 2
// whole batches; v[b]=4.2MB ~ L2), 4 rows/block, 2 float4/thread, NT stores.
// agg floor ~47us: d_out write-path cap — 8 structural variants all pinned.
// ---------------------------------------------------------------------------
__global__ __launch_bounds__(256) void agg_out(const float* __restrict__ v,
                                               const int* __restrict__ delays,
                                               const float* __restrict__ probs,
                                               float* __restrict__ out){
  const int bid = blockIdx.x;
  const int xcd = bid & 7;
  const int w = bid >> 3;
  const int b = (xcd << 1) + (w >> 9);
  const int local = w & 511;
  const int tid = threadIdx.x;
  const int t = (local << 2) + (tid >> 6);   // 4 rows per block
  const int i0 = tid & 63;                   // float4 slots i0 and i0+64
  const int row = (b << 11) + t;
  f32x4v acc0 = {0.f, 0.f, 0.f, 0.f};
  f32x4v acc1 = {0.f, 0.f, 0.f, 0.f};
#pragma unroll
  for (int kk = 0; kk < TK; ++kk){
    const int d = delays[b * TK + kk];
    const float p = probs[b * TK + kk];
    const int srcr = (t + d) & (LL - 1);
    const size_t base = (size_t)((b << 11) + srcr) * 128;
    const f32x4v x0 = reinterpret_cast<const f32x4v*>(v)[base + i0];
    const f32x4v x1 = reinterpret_cast<const f32x4v*>(v)[base + i0 + 64];
    acc0 += x0 * p;
    acc1 += x1 * p;
  }
  f32x4v* o = reinterpret_cast<f32x4v*>(out) + (size_t)row * 128;
  __builtin_nontemporal_store(acc0, o + i0);
  __builtin_nontemporal_store(acc1, o + i0 + 64);
}

// ---------------------------------------------------------------------------
extern "C" void kernel_launch(void* const* d_in, const int* in_sizes, int n_in,
                              void* d_out, int out_size, void* d_ws, size_t ws_size,
                              hipStream_t stream){
  const float* q = (const float*)d_in[0];
  const float* k = (const float*)d_in[1];
  const float* v = (const float*)d_in[2];
  float* out = (float*)d_out;

  char* ws = (char*)d_ws;
  const size_t Z_BYTES  = (size_t)BB * CC * LL * sizeof(__half2);   // 67.1 MB
  const size_t PP_BYTES = (size_t)BB * NG * PSTR * sizeof(float2);  // 8.65 MB
  const size_t P_BYTES  = (size_t)BB * LL * sizeof(float2);         // 256 KB
  __half2* zbuf = (__half2*)ws;
  float2* Ppart = (float2*)(ws + Z_BYTES);
  float2* Pbuf  = (float2*)(ws + Z_BYTES + PP_BYTES);
  int* delays = (int*)(ws + Z_BYTES + PP_BYTES + P_BYTES);
  float* probs = (float*)(ws + Z_BYTES + PP_BYTES + P_BYTES + 1024);

  hipLaunchKernelGGL(transpose_pack, dim3(BB * 32 * 8), dim3(256), 0, stream, q, k, zbuf);
  hipLaunchKernelGGL(fft_fwd, dim3(BB * NG), dim3(256), 0, stream, zbuf, Ppart);
  hipLaunchKernelGGL(reduce_P, dim3((BB * LL) / 256), dim3(256), 0, stream, Ppart, Pbuf);
  hipLaunchKernelGGL(fft_inv_topk, dim3(BB), dim3(256), 0, stream, Pbuf, delays, probs);
  hipLaunchKernelGGL(agg_out, dim3(BB * 512), dim3(256), 0, stream,
                     v, delays, probs, out);
}